// Round 5
// baseline (548.969 us; speedup 1.0000x reference)
//
#include <hip/hip_runtime.h>
#include <math.h>

// ---------------------------------------------------------------------------
// SheafGNN forward, fp32.
// Once:  CSR-by-col build (hist/scan/fill -> ptr, adjrow, perm).
// h0 = x@Win+b; 2x [pq = h@W1p; k_maps_expm (thread-per-edge, register-only):
//   maps=relu(p[row]+q[col]+b1)@w2+b2 -> expm -> M1,M2 at CSR slot perm[e];
//   k_agg: per-node wave walks CSR segment (unroll-2), fused elu epilogue];
// out = h@Wout+b.
// R4 post-mortem: k_maps_expm was occupancy/latency-bound (Occ 16.7% from
// 33KB LDS, VALU 32%, 640k LDS conflicts). This version: no LDS, h in
// registers (4 chunks of 16), w2/b1/b2 via wave-uniform s_load path.
// ---------------------------------------------------------------------------

__global__ void __launch_bounds__(256) k_pack_w1(const float* __restrict__ w1,
                                                 float* __restrict__ Wp) {
  int t = blockIdx.x * 256 + threadIdx.x;
  if (t >= 128 * 128) return;
  int i = t >> 7, o = t & 127;
  Wp[t] = (o < 64) ? w1[i * 64 + o] : w1[(128 + i) * 64 + (o - 64)];
}

// C(N x P) = A(N x 128) @ W(128 x P) + bias; P is 64 or 128, tile 64x64.
__global__ void __launch_bounds__(256) k_gemm128(const float* __restrict__ A,
    const float* __restrict__ W, const float* __restrict__ bias,
    float* __restrict__ C, int N, int P) {
  __shared__ float As[128 * 65];
  int t = threadIdx.x;
  int nb = blockIdx.x << 6, cb = blockIdx.y << 6;
#pragma unroll
  for (int i = 0; i < 32; ++i) {
    int idx = (i << 8) + t;
    int node = idx >> 7, k = idx & 127;
    float v = 0.f;
    if (nb + node < N) v = A[(size_t)(nb + node) * 128 + k];
    As[k * 65 + node] = v;
  }
  __syncthreads();
  int tx = t & 15, ty = t >> 4;
  int c0 = cb + (tx << 2);
  int n0 = ty << 2;
  float acc[4][4] = {};
  for (int k = 0; k < 128; ++k) {
    float4 wv = *(const float4*)(W + (size_t)k * P + c0);
    float a0 = As[k * 65 + n0 + 0];
    float a1 = As[k * 65 + n0 + 1];
    float a2 = As[k * 65 + n0 + 2];
    float a3 = As[k * 65 + n0 + 3];
    acc[0][0] = fmaf(a0, wv.x, acc[0][0]);
    acc[0][1] = fmaf(a0, wv.y, acc[0][1]);
    acc[0][2] = fmaf(a0, wv.z, acc[0][2]);
    acc[0][3] = fmaf(a0, wv.w, acc[0][3]);
    acc[1][0] = fmaf(a1, wv.x, acc[1][0]);
    acc[1][1] = fmaf(a1, wv.y, acc[1][1]);
    acc[1][2] = fmaf(a1, wv.z, acc[1][2]);
    acc[1][3] = fmaf(a1, wv.w, acc[1][3]);
    acc[2][0] = fmaf(a2, wv.x, acc[2][0]);
    acc[2][1] = fmaf(a2, wv.y, acc[2][1]);
    acc[2][2] = fmaf(a2, wv.z, acc[2][2]);
    acc[2][3] = fmaf(a2, wv.w, acc[2][3]);
    acc[3][0] = fmaf(a3, wv.x, acc[3][0]);
    acc[3][1] = fmaf(a3, wv.y, acc[3][1]);
    acc[3][2] = fmaf(a3, wv.z, acc[3][2]);
    acc[3][3] = fmaf(a3, wv.w, acc[3][3]);
  }
  float4 bv = make_float4(0.f, 0.f, 0.f, 0.f);
  if (bias) bv = *(const float4*)(bias + c0);
#pragma unroll
  for (int i = 0; i < 4; ++i) {
    int n = nb + n0 + i;
    if (n < N) {
      float4 o;
      o.x = acc[i][0] + bv.x;
      o.y = acc[i][1] + bv.y;
      o.z = acc[i][2] + bv.z;
      o.w = acc[i][3] + bv.w;
      *(float4*)(C + (size_t)n * P + c0) = o;
    }
  }
}

// ---- CSR build (by col) ----------------------------------------------------
__global__ void __launch_bounds__(256) k_hist(const int* __restrict__ eidx,
                                              int* __restrict__ cnt, int E) {
  int e = blockIdx.x * 256 + threadIdx.x;
  if (e < E) atomicAdd(&cnt[eidx[E + e]], 1);
}

__global__ void __launch_bounds__(256) k_scan(const int* __restrict__ cnt,
    int* __restrict__ ptr, int* __restrict__ cursor, int N) {
  __shared__ int sums[256];
  int t = threadIdx.x;
  int chunk = (N + 255) / 256;
  int lo = t * chunk;
  int hi = lo + chunk;
  if (hi > N) hi = N;
  if (lo > N) lo = N;
  int s = 0;
  for (int i = lo; i < hi; ++i) s += cnt[i];
  sums[t] = s;
  __syncthreads();
  for (int d = 1; d < 256; d <<= 1) {
    int v = (t >= d) ? sums[t - d] : 0;
    __syncthreads();
    sums[t] += v;
    __syncthreads();
  }
  int run = (t == 0) ? 0 : sums[t - 1];
  for (int i = lo; i < hi; ++i) {
    ptr[i] = run;
    cursor[i] = run;
    run += cnt[i];
  }
  if (t == 255) ptr[N] = run;
}

__global__ void __launch_bounds__(256) k_fill(const int* __restrict__ eidx,
    int* __restrict__ cursor, int* __restrict__ adjrow, int* __restrict__ perm,
    int E) {
  int e = blockIdx.x * 256 + threadIdx.x;
  if (e >= E) return;
  int r = eidx[e], c = eidx[E + e];
  int pos = atomicAdd(&cursor[c], 1);
  adjrow[pos] = r;
  perm[e] = pos;
}

// ---- expm of antisym(4x4): scaling-squaring + Taylor(8), registers only ----
__device__ __forceinline__ void expm4(const float* __restrict__ Min,
                                      float* __restrict__ T) {
  float A[16];
#pragma unroll
  for (int a = 0; a < 4; ++a)
#pragma unroll
    for (int b = 0; b < 4; ++b) A[a * 4 + b] = Min[a * 4 + b] - Min[b * 4 + a];
  float nrm = 0.f;
#pragma unroll
  for (int i = 0; i < 16; ++i) nrm = fmaxf(nrm, fabsf(A[i]));
  int ex = 0;
  (void)frexpf(8.f * nrm, &ex);  // maxabs/2^s <= 1/8
  int s = (nrm > 0.f) ? ((ex < 0) ? 0 : ex) : 0;
  s = (s > 30) ? 30 : s;
  float sc = ldexpf(1.f, -s);
#pragma unroll
  for (int i = 0; i < 16; ++i) A[i] *= sc;
#pragma unroll
  for (int i = 0; i < 16; ++i) T[i] = ((i & 3) == (i >> 2)) ? 1.f : 0.f;
  float P[16];
#pragma unroll
  for (int k = 8; k >= 1; --k) {  // Horner: T = I + (A@T)/k
#pragma unroll
    for (int a = 0; a < 4; ++a)
#pragma unroll
      for (int b = 0; b < 4; ++b) {
        float acc = 0.f;
#pragma unroll
        for (int c = 0; c < 4; ++c) acc = fmaf(A[a * 4 + c], T[c * 4 + b], acc);
        P[a * 4 + b] = acc;
      }
    float rk = 1.f / (float)k;
#pragma unroll
    for (int i = 0; i < 16; ++i)
      T[i] = fmaf(P[i], rk, ((i & 3) == (i >> 2)) ? 1.f : 0.f);
  }
  for (int it = 0; it < s; ++it) {
#pragma unroll
    for (int a = 0; a < 4; ++a)
#pragma unroll
      for (int b = 0; b < 4; ++b) {
        float acc = 0.f;
#pragma unroll
        for (int c = 0; c < 4; ++c) acc = fmaf(T[a * 4 + c], T[c * 4 + b], acc);
        P[a * 4 + b] = acc;
      }
#pragma unroll
    for (int i = 0; i < 16; ++i) T[i] = P[i];
  }
}

// Thread-per-edge, register-only: h in 4 chunks of 16; w2/b1/b2 wave-uniform
// (s_load); fused expm + M1=Fu^T Fu, M2=Fu^T Fv; write to CSR slot perm[e].
__global__ void __launch_bounds__(256) k_maps_expm(const float* __restrict__ pq,
    const float* __restrict__ w2, const float* __restrict__ b1,
    const float* __restrict__ b2, const int* __restrict__ eidx,
    const int* __restrict__ perm, float* __restrict__ MM, int E) {
  int e = blockIdx.x * 256 + threadIdx.x;
  if (e >= E) return;
  int row = eidx[e], col = eidx[E + e];
  const float* pr = pq + (size_t)row * 128;
  const float* qc = pq + (size_t)col * 128 + 64;
  float acc[32];
#pragma unroll
  for (int o = 0; o < 32; ++o) acc[o] = b2[o];  // uniform -> s_load
#pragma unroll
  for (int c = 0; c < 4; ++c) {
    float4 p0 = *(const float4*)(pr + c * 16 + 0);
    float4 p1 = *(const float4*)(pr + c * 16 + 4);
    float4 p2 = *(const float4*)(pr + c * 16 + 8);
    float4 p3 = *(const float4*)(pr + c * 16 + 12);
    float4 q0 = *(const float4*)(qc + c * 16 + 0);
    float4 q1 = *(const float4*)(qc + c * 16 + 4);
    float4 q2 = *(const float4*)(qc + c * 16 + 8);
    float4 q3 = *(const float4*)(qc + c * 16 + 12);
    float h[16];
    h[0] = fmaxf(p0.x + q0.x + b1[c * 16 + 0], 0.f);
    h[1] = fmaxf(p0.y + q0.y + b1[c * 16 + 1], 0.f);
    h[2] = fmaxf(p0.z + q0.z + b1[c * 16 + 2], 0.f);
    h[3] = fmaxf(p0.w + q0.w + b1[c * 16 + 3], 0.f);
    h[4] = fmaxf(p1.x + q1.x + b1[c * 16 + 4], 0.f);
    h[5] = fmaxf(p1.y + q1.y + b1[c * 16 + 5], 0.f);
    h[6] = fmaxf(p1.z + q1.z + b1[c * 16 + 6], 0.f);
    h[7] = fmaxf(p1.w + q1.w + b1[c * 16 + 7], 0.f);
    h[8] = fmaxf(p2.x + q2.x + b1[c * 16 + 8], 0.f);
    h[9] = fmaxf(p2.y + q2.y + b1[c * 16 + 9], 0.f);
    h[10] = fmaxf(p2.z + q2.z + b1[c * 16 + 10], 0.f);
    h[11] = fmaxf(p2.w + q2.w + b1[c * 16 + 11], 0.f);
    h[12] = fmaxf(p3.x + q3.x + b1[c * 16 + 12], 0.f);
    h[13] = fmaxf(p3.y + q3.y + b1[c * 16 + 13], 0.f);
    h[14] = fmaxf(p3.z + q3.z + b1[c * 16 + 14], 0.f);
    h[15] = fmaxf(p3.w + q3.w + b1[c * 16 + 15], 0.f);
#pragma unroll
    for (int m = 0; m < 16; ++m)
#pragma unroll
      for (int o = 0; o < 32; ++o)
        acc[o] = fmaf(h[m], w2[(c * 16 + m) * 32 + o], acc[o]);  // s_load
  }
  float Fu[16], Fv[16];
  expm4(acc, Fu);
  expm4(acc + 16, Fv);
  float out[32];
#pragma unroll
  for (int a = 0; a < 4; ++a)
#pragma unroll
    for (int b = 0; b < 4; ++b) {
      float s1 = 0.f, s2 = 0.f;
#pragma unroll
      for (int c = 0; c < 4; ++c) {
        s1 = fmaf(Fu[c * 4 + a], Fu[c * 4 + b], s1);  // (Fu^T Fu)[a,b]
        s2 = fmaf(Fu[c * 4 + a], Fv[c * 4 + b], s2);  // (Fu^T Fv)[a,b]
      }
      out[a * 4 + b] = s1;
      out[16 + a * 4 + b] = s2;
    }
  float* mp = MM + (size_t)perm[e] * 32;
#pragma unroll
  for (int i = 0; i < 8; ++i) {
    float4 v = make_float4(out[i * 4], out[i * 4 + 1], out[i * 4 + 2],
                           out[i * 4 + 3]);
    *(float4*)(mp + i * 4) = v;
  }
}

// One wave per node: walk CSR segment (unroll-2 for two gather chains in
// flight), acc msg in 2 regs/lane, fused h_out = elu(h - eps*agg). No atomics.
__global__ void __launch_bounds__(256) k_agg(const float* __restrict__ x,
    const float* __restrict__ MM, const int* __restrict__ ptr,
    const int* __restrict__ adjrow, const float* __restrict__ epsp,
    float* __restrict__ xout, int N) {
  int wv = threadIdx.x >> 6, lane = threadIdx.x & 63;
  int v = blockIdx.x * 4 + wv;
  if (v >= N) return;
  int p0 = ptr[v], p1 = ptr[v + 1];
  int a = lane & 3, kb = lane & ~3;
  const float* xv = x + (size_t)v * 128;
  float4 xi1 = *(const float4*)(xv + kb);
  float4 xi2 = *(const float4*)(xv + 64 + kb);
  float hv1 = xv[lane], hv2 = xv[64 + lane];
  float acc1 = 0.f, acc2 = 0.f;
  int j = p0;
  for (; j + 1 < p1; j += 2) {
    int r0 = adjrow[j], r1 = adjrow[j + 1];
    const float* mpa = MM + (size_t)j * 32;
    const float* mpb = MM + (size_t)(j + 1) * 32;
    float4 am1 = *(const float4*)(mpa + a * 4);
    float4 am2 = *(const float4*)(mpa + 16 + a * 4);
    float4 bm1 = *(const float4*)(mpb + a * 4);
    float4 bm2 = *(const float4*)(mpb + 16 + a * 4);
    const float* xa = x + (size_t)r0 * 128;
    const float* xb = x + (size_t)r1 * 128;
    float4 xa1 = *(const float4*)(xa + kb);
    float4 xa2 = *(const float4*)(xa + 64 + kb);
    float4 xb1 = *(const float4*)(xb + kb);
    float4 xb2 = *(const float4*)(xb + 64 + kb);
    acc1 += am1.x * xi1.x + am1.y * xi1.y + am1.z * xi1.z + am1.w * xi1.w -
            (am2.x * xa1.x + am2.y * xa1.y + am2.z * xa1.z + am2.w * xa1.w);
    acc2 += am1.x * xi2.x + am1.y * xi2.y + am1.z * xi2.z + am1.w * xi2.w -
            (am2.x * xa2.x + am2.y * xa2.y + am2.z * xa2.z + am2.w * xa2.w);
    acc1 += bm1.x * xi1.x + bm1.y * xi1.y + bm1.z * xi1.z + bm1.w * xi1.w -
            (bm2.x * xb1.x + bm2.y * xb1.y + bm2.z * xb1.z + bm2.w * xb1.w);
    acc2 += bm1.x * xi2.x + bm1.y * xi2.y + bm1.z * xi2.z + bm1.w * xi2.w -
            (bm2.x * xb2.x + bm2.y * xb2.y + bm2.z * xb2.z + bm2.w * xb2.w);
  }
  if (j < p1) {
    int r0 = adjrow[j];
    const float* mpa = MM + (size_t)j * 32;
    float4 am1 = *(const float4*)(mpa + a * 4);
    float4 am2 = *(const float4*)(mpa + 16 + a * 4);
    const float* xa = x + (size_t)r0 * 128;
    float4 xa1 = *(const float4*)(xa + kb);
    float4 xa2 = *(const float4*)(xa + 64 + kb);
    acc1 += am1.x * xi1.x + am1.y * xi1.y + am1.z * xi1.z + am1.w * xi1.w -
            (am2.x * xa1.x + am2.y * xa1.y + am2.z * xa1.z + am2.w * xa1.w);
    acc2 += am1.x * xi2.x + am1.y * xi2.y + am1.z * xi2.z + am1.w * xi2.w -
            (am2.x * xa2.x + am2.y * xa2.y + am2.z * xa2.z + am2.w * xa2.w);
  }
  float eps = *epsp;
  float r1 = hv1 - eps * acc1;
  float r2 = hv2 - eps * acc2;
  r1 = (r1 > 0.f) ? r1 : expm1f(r1);
  r2 = (r2 > 0.f) ? r2 : expm1f(r2);
  xout[(size_t)v * 128 + lane] = r1;
  xout[(size_t)v * 128 + 64 + lane] = r2;
}

extern "C" void kernel_launch(void* const* d_in, const int* in_sizes, int n_in,
                              void* d_out, int out_size, void* d_ws,
                              size_t ws_size, hipStream_t stream) {
  const float* x = (const float*)d_in[0];
  const int* eidx = (const int*)d_in[1];
  const float* lin_in_w = (const float*)d_in[2];
  const float* lin_in_b = (const float*)d_in[3];
  const float* c0w1 = (const float*)d_in[4];
  const float* c0b1 = (const float*)d_in[5];
  const float* c0w2 = (const float*)d_in[6];
  const float* c0b2 = (const float*)d_in[7];
  const float* c0eps = (const float*)d_in[8];
  const float* c1w1 = (const float*)d_in[9];
  const float* c1b1 = (const float*)d_in[10];
  const float* c1w2 = (const float*)d_in[11];
  const float* c1b2 = (const float*)d_in[12];
  const float* c1eps = (const float*)d_in[13];
  const float* lout_w = (const float*)d_in[14];
  const float* lout_b = (const float*)d_in[15];
  float* out = (float*)d_out;

  int N = in_sizes[0] / 128;
  int E = in_sizes[1] / 2;

  char* ws = (char*)d_ws;
  size_t szH = (size_t)N * 128 * sizeof(float);
  float* H = (float*)ws;
  float* H2 = (float*)(ws + szH);
  float* PQ = (float*)(ws + 2 * szH);
  float* WP = (float*)(ws + 3 * szH);                    // 64 KB
  float* MAPS = (float*)(ws + 3 * szH + (1 << 20));      // E*32 floats
  char* ip = ws + 3 * szH + (1 << 20) + (size_t)E * 32 * sizeof(float);
  int* cnt = (int*)ip;                                   // N
  int* ptr = (int*)(ip + 4 * (size_t)(N + 64));          // N+1
  int* cursor = (int*)(ip + 8 * (size_t)(N + 64));       // N
  int* adjrow = (int*)(ip + 12 * (size_t)(N + 64));      // E
  int* perm = (int*)(ip + 12 * (size_t)(N + 64) + 4 * (size_t)E);  // E

  dim3 blk(256);
  int gN = (N + 63) / 64;
  int gE = (E + 255) / 256;

  // CSR build (edge_index shared by both conv layers)
  hipMemsetAsync(cnt, 0, (size_t)N * 4, stream);
  k_hist<<<gE, blk, 0, stream>>>(eidx, cnt, E);
  k_scan<<<1, blk, 0, stream>>>(cnt, ptr, cursor, N);
  k_fill<<<gE, blk, 0, stream>>>(eidx, cursor, adjrow, perm, E);

  // h0 = x @ lin_in_w + lin_in_b
  k_gemm128<<<dim3(gN, 2), blk, 0, stream>>>(x, lin_in_w, lin_in_b, H, N, 128);

  float* cur = H;
  float* nxt = H2;
  for (int layer = 0; layer < 2; ++layer) {
    const float* w1 = layer ? c1w1 : c0w1;
    const float* b1 = layer ? c1b1 : c0b1;
    const float* w2 = layer ? c1w2 : c0w2;
    const float* b2 = layer ? c1b2 : c0b2;
    const float* ep = layer ? c1eps : c0eps;
    k_pack_w1<<<64, blk, 0, stream>>>(w1, WP);
    k_gemm128<<<dim3(gN, 2), blk, 0, stream>>>(cur, WP, nullptr, PQ, N, 128);
    k_maps_expm<<<gE, blk, 0, stream>>>(PQ, w2, b1, b2, eidx, perm, MAPS, E);
    k_agg<<<(N + 3) / 4, blk, 0, stream>>>(cur, MAPS, ptr, adjrow, ep, nxt, N);
    float* tmp = cur;
    cur = nxt;
    nxt = tmp;
  }

  k_gemm128<<<dim3(gN, 1), blk, 0, stream>>>(cur, lout_w, lout_b, out, N, 64);
}

// Round 7
// 452.590 us; speedup vs baseline: 1.2130x; 1.2130x over previous
//
#include <hip/hip_runtime.h>
#include <math.h>

// ---------------------------------------------------------------------------
// SheafGNN forward, fp32.
// Once:  CSR-by-col build (hist/scan/fill -> ptr, adjrow, perm).
// h0 = x@Win+b; 2x [pq = h@W1p; k_maps_expm (coalesced LDS staging, K split
//   into 2 chunks of 32 feats -> 16.9KB LDS): maps = relu(p[row]+q[col]+b1)
//   @w2+b2 -> expm -> M1,M2 at CSR slot perm[e]; k_agg: per-node wave walks
//   CSR segment (unroll-2), fused elu epilogue]; out = h@Wout+b.
// R6 post-mortem: core dump; all addressing audited in-bounds. Suspect the
// conditional __syncthreads inside an unrolled loop (convergence miscompile
// risk). This version: STRAIGHT-LINE barriers (stage0/sync/fma0/sync/
// stage1/sync/fma1), no barrier under a conditional or unrolled loop.
// ---------------------------------------------------------------------------

__global__ void __launch_bounds__(256) k_pack_w1(const float* __restrict__ w1,
                                                 float* __restrict__ Wp) {
  int t = blockIdx.x * 256 + threadIdx.x;
  if (t >= 128 * 128) return;
  int i = t >> 7, o = t & 127;
  Wp[t] = (o < 64) ? w1[i * 64 + o] : w1[(128 + i) * 64 + (o - 64)];
}

// C(N x P) = A(N x 128) @ W(128 x P) + bias; P is 64 or 128, tile 64x64.
__global__ void __launch_bounds__(256) k_gemm128(const float* __restrict__ A,
    const float* __restrict__ W, const float* __restrict__ bias,
    float* __restrict__ C, int N, int P) {
  __shared__ float As[128 * 65];
  int t = threadIdx.x;
  int nb = blockIdx.x << 6, cb = blockIdx.y << 6;
#pragma unroll
  for (int i = 0; i < 32; ++i) {
    int idx = (i << 8) + t;
    int node = idx >> 7, k = idx & 127;
    float v = 0.f;
    if (nb + node < N) v = A[(size_t)(nb + node) * 128 + k];
    As[k * 65 + node] = v;
  }
  __syncthreads();
  int tx = t & 15, ty = t >> 4;
  int c0 = cb + (tx << 2);
  int n0 = ty << 2;
  float acc[4][4] = {};
  for (int k = 0; k < 128; ++k) {
    float4 wv = *(const float4*)(W + (size_t)k * P + c0);
    float a0 = As[k * 65 + n0 + 0];
    float a1 = As[k * 65 + n0 + 1];
    float a2 = As[k * 65 + n0 + 2];
    float a3 = As[k * 65 + n0 + 3];
    acc[0][0] = fmaf(a0, wv.x, acc[0][0]);
    acc[0][1] = fmaf(a0, wv.y, acc[0][1]);
    acc[0][2] = fmaf(a0, wv.z, acc[0][2]);
    acc[0][3] = fmaf(a0, wv.w, acc[0][3]);
    acc[1][0] = fmaf(a1, wv.x, acc[1][0]);
    acc[1][1] = fmaf(a1, wv.y, acc[1][1]);
    acc[1][2] = fmaf(a1, wv.z, acc[1][2]);
    acc[1][3] = fmaf(a1, wv.w, acc[1][3]);
    acc[2][0] = fmaf(a2, wv.x, acc[2][0]);
    acc[2][1] = fmaf(a2, wv.y, acc[2][1]);
    acc[2][2] = fmaf(a2, wv.z, acc[2][2]);
    acc[2][3] = fmaf(a2, wv.w, acc[2][3]);
    acc[3][0] = fmaf(a3, wv.x, acc[3][0]);
    acc[3][1] = fmaf(a3, wv.y, acc[3][1]);
    acc[3][2] = fmaf(a3, wv.z, acc[3][2]);
    acc[3][3] = fmaf(a3, wv.w, acc[3][3]);
  }
  float4 bv = make_float4(0.f, 0.f, 0.f, 0.f);
  if (bias) bv = *(const float4*)(bias + c0);
#pragma unroll
  for (int i = 0; i < 4; ++i) {
    int n = nb + n0 + i;
    if (n < N) {
      float4 o;
      o.x = acc[i][0] + bv.x;
      o.y = acc[i][1] + bv.y;
      o.z = acc[i][2] + bv.z;
      o.w = acc[i][3] + bv.w;
      *(float4*)(C + (size_t)n * P + c0) = o;
    }
  }
}

// ---- CSR build (by col) ----------------------------------------------------
__global__ void __launch_bounds__(256) k_hist(const int* __restrict__ eidx,
                                              int* __restrict__ cnt, int E) {
  int e = blockIdx.x * 256 + threadIdx.x;
  if (e < E) atomicAdd(&cnt[eidx[E + e]], 1);
}

__global__ void __launch_bounds__(256) k_scan(const int* __restrict__ cnt,
    int* __restrict__ ptr, int* __restrict__ cursor, int N) {
  __shared__ int sums[256];
  int t = threadIdx.x;
  int chunk = (N + 255) / 256;
  int lo = t * chunk;
  int hi = lo + chunk;
  if (hi > N) hi = N;
  if (lo > N) lo = N;
  int s = 0;
  for (int i = lo; i < hi; ++i) s += cnt[i];
  sums[t] = s;
  __syncthreads();
  for (int d = 1; d < 256; d <<= 1) {
    int v = (t >= d) ? sums[t - d] : 0;
    __syncthreads();
    sums[t] += v;
    __syncthreads();
  }
  int run = (t == 0) ? 0 : sums[t - 1];
  for (int i = lo; i < hi; ++i) {
    ptr[i] = run;
    cursor[i] = run;
    run += cnt[i];
  }
  if (t == 255) ptr[N] = run;
}

__global__ void __launch_bounds__(256) k_fill(const int* __restrict__ eidx,
    int* __restrict__ cursor, int* __restrict__ adjrow, int* __restrict__ perm,
    int E) {
  int e = blockIdx.x * 256 + threadIdx.x;
  if (e >= E) return;
  int r = eidx[e], c = eidx[E + e];
  int pos = atomicAdd(&cursor[c], 1);
  adjrow[pos] = r;
  perm[e] = pos;
}

// ---- expm of antisym(4x4): scaling-squaring + Taylor(8), registers only ----
__device__ __forceinline__ void expm4(const float* __restrict__ Min,
                                      float* __restrict__ T) {
  float A[16];
#pragma unroll
  for (int a = 0; a < 4; ++a)
#pragma unroll
    for (int b = 0; b < 4; ++b) A[a * 4 + b] = Min[a * 4 + b] - Min[b * 4 + a];
  float nrm = 0.f;
#pragma unroll
  for (int i = 0; i < 16; ++i) nrm = fmaxf(nrm, fabsf(A[i]));
  int ex = 0;
  (void)frexpf(8.f * nrm, &ex);  // maxabs/2^s <= 1/8
  int s = (nrm > 0.f) ? ((ex < 0) ? 0 : ex) : 0;
  s = (s > 30) ? 30 : s;
  float sc = ldexpf(1.f, -s);
#pragma unroll
  for (int i = 0; i < 16; ++i) A[i] *= sc;
#pragma unroll
  for (int i = 0; i < 16; ++i) T[i] = ((i & 3) == (i >> 2)) ? 1.f : 0.f;
  float P[16];
#pragma unroll
  for (int k = 8; k >= 1; --k) {  // Horner: T = I + (A@T)/k
#pragma unroll
    for (int a = 0; a < 4; ++a)
#pragma unroll
      for (int b = 0; b < 4; ++b) {
        float acc = 0.f;
#pragma unroll
        for (int c = 0; c < 4; ++c) acc = fmaf(A[a * 4 + c], T[c * 4 + b], acc);
        P[a * 4 + b] = acc;
      }
    float rk = 1.f / (float)k;
#pragma unroll
    for (int i = 0; i < 16; ++i)
      T[i] = fmaf(P[i], rk, ((i & 3) == (i >> 2)) ? 1.f : 0.f);
  }
  for (int it = 0; it < s; ++it) {
#pragma unroll
    for (int a = 0; a < 4; ++a)
#pragma unroll
      for (int b = 0; b < 4; ++b) {
        float acc = 0.f;
#pragma unroll
        for (int c = 0; c < 4; ++c) acc = fmaf(T[a * 4 + c], T[c * 4 + b], acc);
        P[a * 4 + b] = acc;
      }
#pragma unroll
    for (int i = 0; i < 16; ++i) T[i] = P[i];
  }
}

// 128 edges / 128-thread block. Two straight-line K-chunks of 32 features:
// stage (coalesced: 4-lane groups read contiguous 64B of a row) -> sync ->
// FMA (w2 at wave-uniform addresses -> s_load) -> sync -> repeat. LDS
// 32*132*4 = 16.9KB. Then fused expm + M-products, CSR-slot write.
__global__ void __launch_bounds__(128) k_maps_expm(const float* __restrict__ pq,
    const float* __restrict__ w2, const float* __restrict__ b1,
    const float* __restrict__ b2, const int* __restrict__ eidx,
    const int* __restrict__ perm, float* __restrict__ MM, int E) {
  __shared__ float Hst[32 * 132];  // [feat_local][edge], stride 132
  int t = threadIdx.x;
  int w = t >> 6, lane = t & 63;
  int e0 = blockIdx.x * 128;
  int esub = lane >> 2, c4 = lane & 3;
  int rows[4], cols[4];
#pragma unroll
  for (int i = 0; i < 4; ++i) {
    int e = e0 + w * 64 + i * 16 + esub;
    int es = (e < E) ? e : (E - 1);
    rows[i] = eidx[es];
    cols[i] = eidx[E + es];
  }
  float acc[32];
#pragma unroll
  for (int o = 0; o < 32; ++o) acc[o] = b2[o];  // uniform -> s_load

  // ---- chunk 0: features 0..31 ----
#pragma unroll
  for (int i = 0; i < 4; ++i) {
    int eloc = w * 64 + i * 16 + esub;
#pragma unroll
    for (int j = 0; j < 2; ++j) {
      int fl = j * 16 + c4 * 4;
      float4 pv = *(const float4*)(pq + (size_t)rows[i] * 128 + fl);
      float4 qv = *(const float4*)(pq + (size_t)cols[i] * 128 + 64 + fl);
      float4 bv = *(const float4*)(b1 + fl);
      Hst[(fl + 0) * 132 + eloc] = fmaxf(pv.x + qv.x + bv.x, 0.f);
      Hst[(fl + 1) * 132 + eloc] = fmaxf(pv.y + qv.y + bv.y, 0.f);
      Hst[(fl + 2) * 132 + eloc] = fmaxf(pv.z + qv.z + bv.z, 0.f);
      Hst[(fl + 3) * 132 + eloc] = fmaxf(pv.w + qv.w + bv.w, 0.f);
    }
  }
  __syncthreads();
  for (int m = 0; m < 32; ++m) {
    float hm = Hst[m * 132 + t];  // stride-1 across lanes
#pragma unroll
    for (int o = 0; o < 32; ++o)
      acc[o] = fmaf(hm, w2[m * 32 + o], acc[o]);  // s_load
  }
  __syncthreads();

  // ---- chunk 1: features 32..63 ----
#pragma unroll
  for (int i = 0; i < 4; ++i) {
    int eloc = w * 64 + i * 16 + esub;
#pragma unroll
    for (int j = 0; j < 2; ++j) {
      int fl = j * 16 + c4 * 4;
      int f = 32 + fl;
      float4 pv = *(const float4*)(pq + (size_t)rows[i] * 128 + f);
      float4 qv = *(const float4*)(pq + (size_t)cols[i] * 128 + 64 + f);
      float4 bv = *(const float4*)(b1 + f);
      Hst[(fl + 0) * 132 + eloc] = fmaxf(pv.x + qv.x + bv.x, 0.f);
      Hst[(fl + 1) * 132 + eloc] = fmaxf(pv.y + qv.y + bv.y, 0.f);
      Hst[(fl + 2) * 132 + eloc] = fmaxf(pv.z + qv.z + bv.z, 0.f);
      Hst[(fl + 3) * 132 + eloc] = fmaxf(pv.w + qv.w + bv.w, 0.f);
    }
  }
  __syncthreads();
  for (int m = 0; m < 32; ++m) {
    float hm = Hst[m * 132 + t];
#pragma unroll
    for (int o = 0; o < 32; ++o)
      acc[o] = fmaf(hm, w2[(32 + m) * 32 + o], acc[o]);  // s_load
  }

  int e = e0 + t;
  if (e >= E) return;
  float Fu[16], Fv[16];
  expm4(acc, Fu);
  expm4(acc + 16, Fv);
  float out[32];
#pragma unroll
  for (int a = 0; a < 4; ++a)
#pragma unroll
    for (int b = 0; b < 4; ++b) {
      float s1 = 0.f, s2 = 0.f;
#pragma unroll
      for (int c = 0; c < 4; ++c) {
        s1 = fmaf(Fu[c * 4 + a], Fu[c * 4 + b], s1);  // (Fu^T Fu)[a,b]
        s2 = fmaf(Fu[c * 4 + a], Fv[c * 4 + b], s2);  // (Fu^T Fv)[a,b]
      }
      out[a * 4 + b] = s1;
      out[16 + a * 4 + b] = s2;
    }
  float* mp = MM + (size_t)perm[e] * 32;
#pragma unroll
  for (int i = 0; i < 8; ++i) {
    float4 v = make_float4(out[i * 4], out[i * 4 + 1], out[i * 4 + 2],
                           out[i * 4 + 3]);
    *(float4*)(mp + i * 4) = v;
  }
}

// One wave per node: walk CSR segment (unroll-2 for two gather chains in
// flight), acc msg in 2 regs/lane, fused h_out = elu(h - eps*agg). No atomics.
__global__ void __launch_bounds__(256) k_agg(const float* __restrict__ x,
    const float* __restrict__ MM, const int* __restrict__ ptr,
    const int* __restrict__ adjrow, const float* __restrict__ epsp,
    float* __restrict__ xout, int N) {
  int wv = threadIdx.x >> 6, lane = threadIdx.x & 63;
  int v = blockIdx.x * 4 + wv;
  if (v >= N) return;
  int p0 = ptr[v], p1 = ptr[v + 1];
  int a = lane & 3, kb = lane & ~3;
  const float* xv = x + (size_t)v * 128;
  float4 xi1 = *(const float4*)(xv + kb);
  float4 xi2 = *(const float4*)(xv + 64 + kb);
  float hv1 = xv[lane], hv2 = xv[64 + lane];
  float acc1 = 0.f, acc2 = 0.f;
  int j = p0;
  for (; j + 1 < p1; j += 2) {
    int r0 = adjrow[j], r1 = adjrow[j + 1];
    const float* mpa = MM + (size_t)j * 32;
    const float* mpb = MM + (size_t)(j + 1) * 32;
    float4 am1 = *(const float4*)(mpa + a * 4);
    float4 am2 = *(const float4*)(mpa + 16 + a * 4);
    float4 bm1 = *(const float4*)(mpb + a * 4);
    float4 bm2 = *(const float4*)(mpb + 16 + a * 4);
    const float* xa = x + (size_t)r0 * 128;
    const float* xb = x + (size_t)r1 * 128;
    float4 xa1 = *(const float4*)(xa + kb);
    float4 xa2 = *(const float4*)(xa + 64 + kb);
    float4 xb1 = *(const float4*)(xb + kb);
    float4 xb2 = *(const float4*)(xb + 64 + kb);
    acc1 += am1.x * xi1.x + am1.y * xi1.y + am1.z * xi1.z + am1.w * xi1.w -
            (am2.x * xa1.x + am2.y * xa1.y + am2.z * xa1.z + am2.w * xa1.w);
    acc2 += am1.x * xi2.x + am1.y * xi2.y + am1.z * xi2.z + am1.w * xi2.w -
            (am2.x * xa2.x + am2.y * xa2.y + am2.z * xa2.z + am2.w * xa2.w);
    acc1 += bm1.x * xi1.x + bm1.y * xi1.y + bm1.z * xi1.z + bm1.w * xi1.w -
            (bm2.x * xb1.x + bm2.y * xb1.y + bm2.z * xb1.z + bm2.w * xb1.w);
    acc2 += bm1.x * xi2.x + bm1.y * xi2.y + bm1.z * xi2.z + bm1.w * xi2.w -
            (bm2.x * xb2.x + bm2.y * xb2.y + bm2.z * xb2.z + bm2.w * xb2.w);
  }
  if (j < p1) {
    int r0 = adjrow[j];
    const float* mpa = MM + (size_t)j * 32;
    float4 am1 = *(const float4*)(mpa + a * 4);
    float4 am2 = *(const float4*)(mpa + 16 + a * 4);
    const float* xa = x + (size_t)r0 * 128;
    float4 xa1 = *(const float4*)(xa + kb);
    float4 xa2 = *(const float4*)(xa + 64 + kb);
    acc1 += am1.x * xi1.x + am1.y * xi1.y + am1.z * xi1.z + am1.w * xi1.w -
            (am2.x * xa1.x + am2.y * xa1.y + am2.z * xa1.z + am2.w * xa1.w);
    acc2 += am1.x * xi2.x + am1.y * xi2.y + am1.z * xi2.z + am1.w * xi2.w -
            (am2.x * xa2.x + am2.y * xa2.y + am2.z * xa2.z + am2.w * xa2.w);
  }
  float eps = *epsp;
  float r1 = hv1 - eps * acc1;
  float r2 = hv2 - eps * acc2;
  r1 = (r1 > 0.f) ? r1 : expm1f(r1);
  r2 = (r2 > 0.f) ? r2 : expm1f(r2);
  xout[(size_t)v * 128 + lane] = r1;
  xout[(size_t)v * 128 + 64 + lane] = r2;
}

extern "C" void kernel_launch(void* const* d_in, const int* in_sizes, int n_in,
                              void* d_out, int out_size, void* d_ws,
                              size_t ws_size, hipStream_t stream) {
  const float* x = (const float*)d_in[0];
  const int* eidx = (const int*)d_in[1];
  const float* lin_in_w = (const float*)d_in[2];
  const float* lin_in_b = (const float*)d_in[3];
  const float* c0w1 = (const float*)d_in[4];
  const float* c0b1 = (const float*)d_in[5];
  const float* c0w2 = (const float*)d_in[6];
  const float* c0b2 = (const float*)d_in[7];
  const float* c0eps = (const float*)d_in[8];
  const float* c1w1 = (const float*)d_in[9];
  const float* c1b1 = (const float*)d_in[10];
  const float* c1w2 = (const float*)d_in[11];
  const float* c1b2 = (const float*)d_in[12];
  const float* c1eps = (const float*)d_in[13];
  const float* lout_w = (const float*)d_in[14];
  const float* lout_b = (const float*)d_in[15];
  float* out = (float*)d_out;

  int N = in_sizes[0] / 128;
  int E = in_sizes[1] / 2;

  char* ws = (char*)d_ws;
  size_t szH = (size_t)N * 128 * sizeof(float);
  float* H = (float*)ws;
  float* H2 = (float*)(ws + szH);
  float* PQ = (float*)(ws + 2 * szH);
  float* WP = (float*)(ws + 3 * szH);                    // 64 KB
  float* MAPS = (float*)(ws + 3 * szH + (1 << 20));      // E*32 floats
  char* ip = ws + 3 * szH + (1 << 20) + (size_t)E * 32 * sizeof(float);
  int* cnt = (int*)ip;                                   // N
  int* ptr = (int*)(ip + 4 * (size_t)(N + 64));          // N+1
  int* cursor = (int*)(ip + 8 * (size_t)(N + 64));       // N
  int* adjrow = (int*)(ip + 12 * (size_t)(N + 64));      // E
  int* perm = (int*)(ip + 12 * (size_t)(N + 64) + 4 * (size_t)E);  // E

  dim3 blk(256);
  int gN = (N + 63) / 64;
  int gE = (E + 255) / 256;

  // CSR build (edge_index shared by both conv layers)
  hipMemsetAsync(cnt, 0, (size_t)N * 4, stream);
  k_hist<<<gE, blk, 0, stream>>>(eidx, cnt, E);
  k_scan<<<1, blk, 0, stream>>>(cnt, ptr, cursor, N);
  k_fill<<<gE, blk, 0, stream>>>(eidx, cursor, adjrow, perm, E);

  // h0 = x @ lin_in_w + lin_in_b
  k_gemm128<<<dim3(gN, 2), blk, 0, stream>>>(x, lin_in_w, lin_in_b, H, N, 128);

  float* cur = H;
  float* nxt = H2;
  for (int layer = 0; layer < 2; ++layer) {
    const float* w1 = layer ? c1w1 : c0w1;
    const float* b1 = layer ? c1b1 : c0b1;
    const float* w2 = layer ? c1w2 : c0w2;
    const float* b2 = layer ? c1b2 : c0b2;
    const float* ep = layer ? c1eps : c0eps;
    k_pack_w1<<<64, blk, 0, stream>>>(w1, WP);
    k_gemm128<<<dim3(gN, 2), blk, 0, stream>>>(cur, WP, nullptr, PQ, N, 128);
    k_maps_expm<<<(E + 127) / 128, dim3(128), 0, stream>>>(PQ, w2, b1, b2,
                                                           eidx, perm, MAPS, E);
    k_agg<<<(N + 3) / 4, blk, 0, stream>>>(cur, MAPS, ptr, adjrow, ep, nxt, N);
    float* tmp = cur;
    cur = nxt;
    nxt = tmp;
  }

  k_gemm128<<<dim3(gN, 1), blk, 0, stream>>>(cur, lout_w, lout_b, out, N, 64);
}

// Round 8
// 431.651 us; speedup vs baseline: 1.2718x; 1.0485x over previous
//
#include <hip/hip_runtime.h>
#include <math.h>

// ---------------------------------------------------------------------------
// SheafGNN forward, fp32.
// Once:  CSR-by-col build (hist/scan/fill -> ptr, adjrow, perm).
// h0 = x@Win+b; 2x [pq = h@W1p; k_maps_expm: maps=relu(p[row]+q[col]+b1)@w2+b2
//   -> closed-form so(4) expm -> M1,M2 at CSR slot perm[e]; k_agg: per-node
//   wave walks CSR segment (unroll-2), fused elu]; out = h@Wout+b.
// R7 post-mortem: gemm128 was latency-bound (scalar ds_read_b32 chains, 4
// blocks/CU, ~10.5 TF). v2: stride-68 LDS (aligned ds_read_b128 A-frags),
// K chunked by 64 (17.4KB LDS -> 9 blocks/CU), W from global, unroll-4
// batched loads. expm: exact so(4)=su(2)+su(2) closed form replaces
// Taylor+squaring (~170 vs ~1500 VALU).
// ---------------------------------------------------------------------------

__global__ void __launch_bounds__(256) k_pack_w1(const float* __restrict__ w1,
                                                 float* __restrict__ Wp) {
  int t = blockIdx.x * 256 + threadIdx.x;
  if (t >= 128 * 128) return;
  int i = t >> 7, o = t & 127;
  Wp[t] = (o < 64) ? w1[i * 64 + o] : w1[(128 + i) * 64 + (o - 64)];
}

// C(N x P) = A(N x 128) @ W(128 x P) + bias; P is 64 or 128, tile 64x64.
// K chunked by 64; A-frag via aligned ds_read_b128 (stride 68); W global.
__global__ void __launch_bounds__(256) k_gemm128(const float* __restrict__ A,
    const float* __restrict__ W, const float* __restrict__ bias,
    float* __restrict__ C, int N, int P) {
  __shared__ float As[64 * 68];  // [k_local][node], stride 68 (b128-aligned)
  int t = threadIdx.x;
  int nb = blockIdx.x << 6, cb = blockIdx.y << 6;
  int tx = t & 15, ty = t >> 4;
  int c0 = cb + (tx << 2);
  int n0 = ty << 2;
  int node8 = t >> 3;  // 0..31
  int f4 = (t & 7) << 2;  // 0,4,..,28
  const float* Wt = W + c0;
  float acc[4][4] = {};
  for (int kc = 0; kc < 128; kc += 64) {
    __syncthreads();
#pragma unroll
    for (int ii = 0; ii < 2; ++ii) {
      int nd = node8 + ii * 32;
      int gn = nb + nd;
#pragma unroll
      for (int jj = 0; jj < 2; ++jj) {
        int kk = f4 + jj * 32;
        float4 av = make_float4(0.f, 0.f, 0.f, 0.f);
        if (gn < N) av = *(const float4*)(A + (size_t)gn * 128 + kc + kk);
        As[(kk + 0) * 68 + nd] = av.x;
        As[(kk + 1) * 68 + nd] = av.y;
        As[(kk + 2) * 68 + nd] = av.z;
        As[(kk + 3) * 68 + nd] = av.w;
      }
    }
    __syncthreads();
    for (int k = 0; k < 64; k += 4) {
      float4 av0 = *(const float4*)&As[(k + 0) * 68 + n0];
      float4 av1 = *(const float4*)&As[(k + 1) * 68 + n0];
      float4 av2 = *(const float4*)&As[(k + 2) * 68 + n0];
      float4 av3 = *(const float4*)&As[(k + 3) * 68 + n0];
      float4 wv0 = *(const float4*)(Wt + (size_t)(kc + k + 0) * P);
      float4 wv1 = *(const float4*)(Wt + (size_t)(kc + k + 1) * P);
      float4 wv2 = *(const float4*)(Wt + (size_t)(kc + k + 2) * P);
      float4 wv3 = *(const float4*)(Wt + (size_t)(kc + k + 3) * P);
#pragma unroll
    for (int j = 0; j < 4; ++j) {
        float4 av = (j == 0) ? av0 : (j == 1) ? av1 : (j == 2) ? av2 : av3;
        float4 wv = (j == 0) ? wv0 : (j == 1) ? wv1 : (j == 2) ? wv2 : wv3;
        acc[0][0] = fmaf(av.x, wv.x, acc[0][0]);
        acc[0][1] = fmaf(av.x, wv.y, acc[0][1]);
        acc[0][2] = fmaf(av.x, wv.z, acc[0][2]);
        acc[0][3] = fmaf(av.x, wv.w, acc[0][3]);
        acc[1][0] = fmaf(av.y, wv.x, acc[1][0]);
        acc[1][1] = fmaf(av.y, wv.y, acc[1][1]);
        acc[1][2] = fmaf(av.y, wv.z, acc[1][2]);
        acc[1][3] = fmaf(av.y, wv.w, acc[1][3]);
        acc[2][0] = fmaf(av.z, wv.x, acc[2][0]);
        acc[2][1] = fmaf(av.z, wv.y, acc[2][1]);
        acc[2][2] = fmaf(av.z, wv.z, acc[2][2]);
        acc[2][3] = fmaf(av.z, wv.w, acc[2][3]);
        acc[3][0] = fmaf(av.w, wv.x, acc[3][0]);
        acc[3][1] = fmaf(av.w, wv.y, acc[3][1]);
        acc[3][2] = fmaf(av.w, wv.z, acc[3][2]);
        acc[3][3] = fmaf(av.w, wv.w, acc[3][3]);
      }
    }
  }
  float4 bv = make_float4(0.f, 0.f, 0.f, 0.f);
  if (bias) bv = *(const float4*)(bias + c0);
#pragma unroll
  for (int i = 0; i < 4; ++i) {
    int n = nb + n0 + i;
    if (n < N) {
      float4 o;
      o.x = acc[i][0] + bv.x;
      o.y = acc[i][1] + bv.y;
      o.z = acc[i][2] + bv.z;
      o.w = acc[i][3] + bv.w;
      *(float4*)(C + (size_t)n * P + c0) = o;
    }
  }
}

// ---- CSR build (by col) ----------------------------------------------------
__global__ void __launch_bounds__(256) k_hist(const int* __restrict__ eidx,
                                              int* __restrict__ cnt, int E) {
  int e = blockIdx.x * 256 + threadIdx.x;
  if (e < E) atomicAdd(&cnt[eidx[E + e]], 1);
}

__global__ void __launch_bounds__(256) k_scan(const int* __restrict__ cnt,
    int* __restrict__ ptr, int* __restrict__ cursor, int N) {
  __shared__ int sums[256];
  int t = threadIdx.x;
  int chunk = (N + 255) / 256;
  int lo = t * chunk;
  int hi = lo + chunk;
  if (hi > N) hi = N;
  if (lo > N) lo = N;
  int s = 0;
  for (int i = lo; i < hi; ++i) s += cnt[i];
  sums[t] = s;
  __syncthreads();
  for (int d = 1; d < 256; d <<= 1) {
    int v = (t >= d) ? sums[t - d] : 0;
    __syncthreads();
    sums[t] += v;
    __syncthreads();
  }
  int run = (t == 0) ? 0 : sums[t - 1];
  for (int i = lo; i < hi; ++i) {
    ptr[i] = run;
    cursor[i] = run;
    run += cnt[i];
  }
  if (t == 255) ptr[N] = run;
}

__global__ void __launch_bounds__(256) k_fill(const int* __restrict__ eidx,
    int* __restrict__ cursor, int* __restrict__ adjrow, int* __restrict__ perm,
    int E) {
  int e = blockIdx.x * 256 + threadIdx.x;
  if (e >= E) return;
  int r = eidx[e], c = eidx[E + e];
  int pos = atomicAdd(&cursor[c], 1);
  adjrow[pos] = r;
  perm[e] = pos;
}

// ---- exact expm of antisym 4x4 via so(4) = su(2) + su(2) -------------------
// A decomposes into commuting A+ (self-dual) and A- (anti-self-dual), each
// with (A+-)^2 = -theta^2 I. exp(A) = (c+ I + s+ A+)(c- I + s- A-).
__device__ __forceinline__ void so4_expm(const float* __restrict__ m,
                                         float* __restrict__ F) {
  float v1 = m[1] - m[4], v2 = m[2] - m[8], v3 = m[3] - m[12];
  float w1 = m[11] - m[14], w2 = m[13] - m[7], w3 = m[6] - m[9];
  float p1 = 0.5f * (v1 + w1), p2 = 0.5f * (v2 + w2), p3 = 0.5f * (v3 + w3);
  float q1 = 0.5f * (v1 - w1), q2 = 0.5f * (v2 - w2), q3 = 0.5f * (v3 - w3);
  float tp2 = p1 * p1 + p2 * p2 + p3 * p3;
  float tq2 = q1 * q1 + q2 * q2 + q3 * q3;
  float tp = sqrtf(tp2), tq = sqrtf(tq2);
  float cp = __cosf(tp);
  float sp = (tp > 1e-6f) ? (__sinf(tp) / tp) : (1.f - tp2 * (1.f / 6.f));
  float cq = __cosf(tq);
  float sq = (tq > 1e-6f) ? (__sinf(tq) / tq) : (1.f - tq2 * (1.f / 6.f));
  float a1 = sp * p1, a2 = sp * p2, a3 = sp * p3;
  float b1 = sq * q1, b2 = sq * q2, b3 = sq * q3;
  float Rp[16] = {cp,  a1,  a2,  a3,  -a1, cp,  a3,  -a2,
                  -a2, -a3, cp,  a1,  -a3, a2,  -a1, cp};
  float Rq[16] = {cq,  b1,  b2,  b3,  -b1, cq,  -b3, b2,
                  -b2, b3,  cq,  -b1, -b3, -b2, b1,  cq};
#pragma unroll
  for (int a = 0; a < 4; ++a)
#pragma unroll
    for (int b = 0; b < 4; ++b) {
      float s = 0.f;
#pragma unroll
      for (int c = 0; c < 4; ++c) s = fmaf(Rp[a * 4 + c], Rq[c * 4 + b], s);
      F[a * 4 + b] = s;
    }
}

// 128 edges / 128-thread block. Two straight-line K-chunks of 32 features:
// stage (coalesced) -> sync -> FMA (w2 wave-uniform s_load) -> sync -> repeat.
// LDS 32*132*4 = 16.9KB. Then closed-form expm + M-products, CSR-slot write.
__global__ void __launch_bounds__(128) k_maps_expm(const float* __restrict__ pq,
    const float* __restrict__ w2, const float* __restrict__ b1,
    const float* __restrict__ b2, const int* __restrict__ eidx,
    const int* __restrict__ perm, float* __restrict__ MM, int E) {
  __shared__ float Hst[32 * 132];  // [feat_local][edge], stride 132
  int t = threadIdx.x;
  int w = t >> 6, lane = t & 63;
  int e0 = blockIdx.x * 128;
  int esub = lane >> 2, c4 = lane & 3;
  int rows[4], cols[4];
#pragma unroll
  for (int i = 0; i < 4; ++i) {
    int e = e0 + w * 64 + i * 16 + esub;
    int es = (e < E) ? e : (E - 1);
    rows[i] = eidx[es];
    cols[i] = eidx[E + es];
  }
  float acc[32];
#pragma unroll
  for (int o = 0; o < 32; ++o) acc[o] = b2[o];  // uniform -> s_load

  // ---- chunk 0: features 0..31 ----
#pragma unroll
  for (int i = 0; i < 4; ++i) {
    int eloc = w * 64 + i * 16 + esub;
#pragma unroll
    for (int j = 0; j < 2; ++j) {
      int fl = j * 16 + c4 * 4;
      float4 pv = *(const float4*)(pq + (size_t)rows[i] * 128 + fl);
      float4 qv = *(const float4*)(pq + (size_t)cols[i] * 128 + 64 + fl);
      float4 bv = *(const float4*)(b1 + fl);
      Hst[(fl + 0) * 132 + eloc] = fmaxf(pv.x + qv.x + bv.x, 0.f);
      Hst[(fl + 1) * 132 + eloc] = fmaxf(pv.y + qv.y + bv.y, 0.f);
      Hst[(fl + 2) * 132 + eloc] = fmaxf(pv.z + qv.z + bv.z, 0.f);
      Hst[(fl + 3) * 132 + eloc] = fmaxf(pv.w + qv.w + bv.w, 0.f);
    }
  }
  __syncthreads();
  for (int m = 0; m < 32; ++m) {
    float hm = Hst[m * 132 + t];  // stride-1 across lanes
#pragma unroll
    for (int o = 0; o < 32; ++o)
      acc[o] = fmaf(hm, w2[m * 32 + o], acc[o]);  // s_load
  }
  __syncthreads();

  // ---- chunk 1: features 32..63 ----
#pragma unroll
  for (int i = 0; i < 4; ++i) {
    int eloc = w * 64 + i * 16 + esub;
#pragma unroll
    for (int j = 0; j < 2; ++j) {
      int fl = j * 16 + c4 * 4;
      int f = 32 + fl;
      float4 pv = *(const float4*)(pq + (size_t)rows[i] * 128 + f);
      float4 qv = *(const float4*)(pq + (size_t)cols[i] * 128 + 64 + f);
      float4 bv = *(const float4*)(b1 + f);
      Hst[(fl + 0) * 132 + eloc] = fmaxf(pv.x + qv.x + bv.x, 0.f);
      Hst[(fl + 1) * 132 + eloc] = fmaxf(pv.y + qv.y + bv.y, 0.f);
      Hst[(fl + 2) * 132 + eloc] = fmaxf(pv.z + qv.z + bv.z, 0.f);
      Hst[(fl + 3) * 132 + eloc] = fmaxf(pv.w + qv.w + bv.w, 0.f);
    }
  }
  __syncthreads();
  for (int m = 0; m < 32; ++m) {
    float hm = Hst[m * 132 + t];
#pragma unroll
    for (int o = 0; o < 32; ++o)
      acc[o] = fmaf(hm, w2[(32 + m) * 32 + o], acc[o]);  // s_load
  }

  int e = e0 + t;
  if (e >= E) return;
  float Fu[16], Fv[16];
  so4_expm(acc, Fu);
  so4_expm(acc + 16, Fv);
  float out[32];
#pragma unroll
  for (int a = 0; a < 4; ++a)
#pragma unroll
    for (int b = 0; b < 4; ++b) {
      float s1 = 0.f, s2 = 0.f;
#pragma unroll
      for (int c = 0; c < 4; ++c) {
        s1 = fmaf(Fu[c * 4 + a], Fu[c * 4 + b], s1);  // (Fu^T Fu)[a,b]
        s2 = fmaf(Fu[c * 4 + a], Fv[c * 4 + b], s2);  // (Fu^T Fv)[a,b]
      }
      out[a * 4 + b] = s1;
      out[16 + a * 4 + b] = s2;
    }
  float* mp = MM + (size_t)perm[e] * 32;
#pragma unroll
  for (int i = 0; i < 8; ++i) {
    float4 v = make_float4(out[i * 4], out[i * 4 + 1], out[i * 4 + 2],
                           out[i * 4 + 3]);
    *(float4*)(mp + i * 4) = v;
  }
}

// One wave per node: walk CSR segment (unroll-2 for two gather chains in
// flight), acc msg in 2 regs/lane, fused h_out = elu(h - eps*agg). No atomics.
__global__ void __launch_bounds__(256) k_agg(const float* __restrict__ x,
    const float* __restrict__ MM, const int* __restrict__ ptr,
    const int* __restrict__ adjrow, const float* __restrict__ epsp,
    float* __restrict__ xout, int N) {
  int wv = threadIdx.x >> 6, lane = threadIdx.x & 63;
  int v = blockIdx.x * 4 + wv;
  if (v >= N) return;
  int p0 = ptr[v], p1 = ptr[v + 1];
  int a = lane & 3, kb = lane & ~3;
  const float* xv = x + (size_t)v * 128;
  float4 xi1 = *(const float4*)(xv + kb);
  float4 xi2 = *(const float4*)(xv + 64 + kb);
  float hv1 = xv[lane], hv2 = xv[64 + lane];
  float acc1 = 0.f, acc2 = 0.f;
  int j = p0;
  for (; j + 1 < p1; j += 2) {
    int r0 = adjrow[j], r1 = adjrow[j + 1];
    const float* mpa = MM + (size_t)j * 32;
    const float* mpb = MM + (size_t)(j + 1) * 32;
    float4 am1 = *(const float4*)(mpa + a * 4);
    float4 am2 = *(const float4*)(mpa + 16 + a * 4);
    float4 bm1 = *(const float4*)(mpb + a * 4);
    float4 bm2 = *(const float4*)(mpb + 16 + a * 4);
    const float* xa = x + (size_t)r0 * 128;
    const float* xb = x + (size_t)r1 * 128;
    float4 xa1 = *(const float4*)(xa + kb);
    float4 xa2 = *(const float4*)(xa + 64 + kb);
    float4 xb1 = *(const float4*)(xb + kb);
    float4 xb2 = *(const float4*)(xb + 64 + kb);
    acc1 += am1.x * xi1.x + am1.y * xi1.y + am1.z * xi1.z + am1.w * xi1.w -
            (am2.x * xa1.x + am2.y * xa1.y + am2.z * xa1.z + am2.w * xa1.w);
    acc2 += am1.x * xi2.x + am1.y * xi2.y + am1.z * xi2.z + am1.w * xi2.w -
            (am2.x * xa2.x + am2.y * xa2.y + am2.z * xa2.z + am2.w * xa2.w);
    acc1 += bm1.x * xi1.x + bm1.y * xi1.y + bm1.z * xi1.z + bm1.w * xi1.w -
            (bm2.x * xb1.x + bm2.y * xb1.y + bm2.z * xb1.z + bm2.w * xb1.w);
    acc2 += bm1.x * xi2.x + bm1.y * xi2.y + bm1.z * xi2.z + bm1.w * xi2.w -
            (bm2.x * xb2.x + bm2.y * xb2.y + bm2.z * xb2.z + bm2.w * xb2.w);
  }
  if (j < p1) {
    int r0 = adjrow[j];
    const float* mpa = MM + (size_t)j * 32;
    float4 am1 = *(const float4*)(mpa + a * 4);
    float4 am2 = *(const float4*)(mpa + 16 + a * 4);
    const float* xa = x + (size_t)r0 * 128;
    float4 xa1 = *(const float4*)(xa + kb);
    float4 xa2 = *(const float4*)(xa + 64 + kb);
    acc1 += am1.x * xi1.x + am1.y * xi1.y + am1.z * xi1.z + am1.w * xi1.w -
            (am2.x * xa1.x + am2.y * xa1.y + am2.z * xa1.z + am2.w * xa1.w);
    acc2 += am1.x * xi2.x + am1.y * xi2.y + am1.z * xi2.z + am1.w * xi2.w -
            (am2.x * xa2.x + am2.y * xa2.y + am2.z * xa2.z + am2.w * xa2.w);
  }
  float eps = *epsp;
  float r1 = hv1 - eps * acc1;
  float r2 = hv2 - eps * acc2;
  r1 = (r1 > 0.f) ? r1 : expm1f(r1);
  r2 = (r2 > 0.f) ? r2 : expm1f(r2);
  xout[(size_t)v * 128 + lane] = r1;
  xout[(size_t)v * 128 + 64 + lane] = r2;
}

extern "C" void kernel_launch(void* const* d_in, const int* in_sizes, int n_in,
                              void* d_out, int out_size, void* d_ws,
                              size_t ws_size, hipStream_t stream) {
  const float* x = (const float*)d_in[0];
  const int* eidx = (const int*)d_in[1];
  const float* lin_in_w = (const float*)d_in[2];
  const float* lin_in_b = (const float*)d_in[3];
  const float* c0w1 = (const float*)d_in[4];
  const float* c0b1 = (const float*)d_in[5];
  const float* c0w2 = (const float*)d_in[6];
  const float* c0b2 = (const float*)d_in[7];
  const float* c0eps = (const float*)d_in[8];
  const float* c1w1 = (const float*)d_in[9];
  const float* c1b1 = (const float*)d_in[10];
  const float* c1w2 = (const float*)d_in[11];
  const float* c1b2 = (const float*)d_in[12];
  const float* c1eps = (const float*)d_in[13];
  const float* lout_w = (const float*)d_in[14];
  const float* lout_b = (const float*)d_in[15];
  float* out = (float*)d_out;

  int N = in_sizes[0] / 128;
  int E = in_sizes[1] / 2;

  char* ws = (char*)d_ws;
  size_t szH = (size_t)N * 128 * sizeof(float);
  float* H = (float*)ws;
  float* H2 = (float*)(ws + szH);
  float* PQ = (float*)(ws + 2 * szH);
  float* WP = (float*)(ws + 3 * szH);                    // 64 KB
  float* MAPS = (float*)(ws + 3 * szH + (1 << 20));      // E*32 floats
  char* ip = ws + 3 * szH + (1 << 20) + (size_t)E * 32 * sizeof(float);
  int* cnt = (int*)ip;                                   // N
  int* ptr = (int*)(ip + 4 * (size_t)(N + 64));          // N+1
  int* cursor = (int*)(ip + 8 * (size_t)(N + 64));       // N
  int* adjrow = (int*)(ip + 12 * (size_t)(N + 64));      // E
  int* perm = (int*)(ip + 12 * (size_t)(N + 64) + 4 * (size_t)E);  // E

  dim3 blk(256);
  int gN = (N + 63) / 64;
  int gE = (E + 255) / 256;

  // CSR build (edge_index shared by both conv layers)
  hipMemsetAsync(cnt, 0, (size_t)N * 4, stream);
  k_hist<<<gE, blk, 0, stream>>>(eidx, cnt, E);
  k_scan<<<1, blk, 0, stream>>>(cnt, ptr, cursor, N);
  k_fill<<<gE, blk, 0, stream>>>(eidx, cursor, adjrow, perm, E);

  // h0 = x @ lin_in_w + lin_in_b
  k_gemm128<<<dim3(gN, 2), blk, 0, stream>>>(x, lin_in_w, lin_in_b, H, N, 128);

  float* cur = H;
  float* nxt = H2;
  for (int layer = 0; layer < 2; ++layer) {
    const float* w1 = layer ? c1w1 : c0w1;
    const float* b1 = layer ? c1b1 : c0b1;
    const float* w2 = layer ? c1w2 : c0w2;
    const float* b2 = layer ? c1b2 : c0b2;
    const float* ep = layer ? c1eps : c0eps;
    k_pack_w1<<<64, blk, 0, stream>>>(w1, WP);
    k_gemm128<<<dim3(gN, 2), blk, 0, stream>>>(cur, WP, nullptr, PQ, N, 128);
    k_maps_expm<<<(E + 127) / 128, dim3(128), 0, stream>>>(PQ, w2, b1, b2,
                                                           eidx, perm, MAPS, E);
    k_agg<<<(N + 3) / 4, blk, 0, stream>>>(cur, MAPS, ptr, adjrow, ep, nxt, N);
    float* tmp = cur;
    cur = nxt;
    nxt = tmp;
  }

  k_gemm128<<<dim3(gN, 1), blk, 0, stream>>>(cur, lout_w, lout_b, out, N, 64);
}

// Round 9
// 400.273 us; speedup vs baseline: 1.3715x; 1.0784x over previous
//
#include <hip/hip_runtime.h>
#include <math.h>

// ---------------------------------------------------------------------------
// SheafGNN forward.
// R9: node GEMMs -> bf16 MFMA (mfma_f32_16x16x32_bf16), LDS-free.
//   A = node features bf16 [Npad][128]; B = W^T bf16 [P][128] (contig K);
//   frag layouts per verified m89/m120 mappings:
//     A[m=lane&15][k=quad*8+j], B[n=lane&15][k=quad*8+j],
//     C/D: col=lane&15, row=quad*4+reg.
//   K=128 = 4 MFMA steps; wave = 16 output cols, 64 rows (4 tiles); block =
//   4 waves = 64x64 tile; grid 313 x P/64. fp32 C out (+ optional bf16 copy).
// R8 post-mortem: fp32 GEMMs were ~50us each, grid-limited (626 blocks =
// 2.4 waves/SIMD) and latency-exposed; closed-form expm was VALU-neutral
// (maps kernel is memory-bound: VALU 25%, time unchanged).
// Rest of pipeline (CSR, k_maps_expm, k_agg) unchanged from R8.
// ---------------------------------------------------------------------------

using short8 = __attribute__((ext_vector_type(8))) short;
using f32x4 = __attribute__((ext_vector_type(4))) float;
typedef unsigned short u16;

__device__ __forceinline__ u16 f2bf(float f) {  // RNE fp32->bf16
  unsigned u = __float_as_uint(f);
  unsigned r = (u + 0x7FFFu + ((u >> 16) & 1u)) >> 16;
  return (u16)r;
}

// ---- one-time packs --------------------------------------------------------
__global__ void __launch_bounds__(256) k_cvt_x(const float* __restrict__ x,
                                               u16* __restrict__ Xb, int n4) {
  int i = blockIdx.x * 256 + threadIdx.x;
  if (i >= n4) return;
  float4 v = ((const float4*)x)[i];
  ushort4 o;
  o.x = f2bf(v.x);
  o.y = f2bf(v.y);
  o.z = f2bf(v.z);
  o.w = f2bf(v.w);
  ((ushort4*)Xb)[i] = o;
}

// WT_in[o][i]=lin_in_w[i][o]; WT1_l[o][i]= packed w1 transpose; WT_out[o][i].
__global__ void __launch_bounds__(256) k_pack_w(const float* __restrict__ win,
    const float* __restrict__ w1a, const float* __restrict__ w1b,
    const float* __restrict__ wout, u16* __restrict__ WTin,
    u16* __restrict__ WT1a, u16* __restrict__ WT1b, u16* __restrict__ WTout) {
  int idx = blockIdx.x * 256 + threadIdx.x;
  if (idx < 16384) {
    int o = idx >> 7, i = idx & 127;
    WTin[idx] = f2bf(win[i * 128 + o]);
  } else if (idx < 32768) {
    int j = idx - 16384;
    int o = j >> 7, i = j & 127;
    WT1a[j] = f2bf(o < 64 ? w1a[i * 64 + o] : w1a[(128 + i) * 64 + (o - 64)]);
  } else if (idx < 49152) {
    int j = idx - 32768;
    int o = j >> 7, i = j & 127;
    WT1b[j] = f2bf(o < 64 ? w1b[i * 64 + o] : w1b[(128 + i) * 64 + (o - 64)]);
  } else if (idx < 57344) {
    int j = idx - 49152;
    int o = j >> 7, i = j & 127;  // o < 64
    WTout[j] = f2bf(wout[i * 64 + o]);
  }
}

// ---- bf16 MFMA GEMM: C[N][P] = A[N][128] @ W[128][P] (+bias) ---------------
__global__ void __launch_bounds__(256) k_gemm_mfma(const u16* __restrict__ Ab,
    const u16* __restrict__ WT, const float* __restrict__ bias,
    float* __restrict__ C, u16* __restrict__ Cb, int N, int P) {
  int t = threadIdx.x;
  int wv = t >> 6, lane = t & 63;
  int nb = blockIdx.x << 6;
  int cb = (blockIdx.y << 6) + (wv << 4);  // this wave's 16 output cols
  int col = lane & 15, quad = lane >> 4;
  const u16* wrow = WT + (size_t)(cb + col) * 128 + quad * 8;
  short8 b0 = *(const short8*)(wrow);
  short8 b1 = *(const short8*)(wrow + 32);
  short8 b2 = *(const short8*)(wrow + 64);
  short8 b3 = *(const short8*)(wrow + 96);
  float bv = bias ? bias[cb + col] : 0.f;
#pragma unroll
  for (int mt = 0; mt < 4; ++mt) {
    const u16* ar = Ab + (size_t)(nb + mt * 16 + col) * 128 + quad * 8;
    short8 a0 = *(const short8*)(ar);
    short8 a1 = *(const short8*)(ar + 32);
    short8 a2 = *(const short8*)(ar + 64);
    short8 a3 = *(const short8*)(ar + 96);
    f32x4 acc = {0.f, 0.f, 0.f, 0.f};
    acc = __builtin_amdgcn_mfma_f32_16x16x32_bf16(a0, b0, acc, 0, 0, 0);
    acc = __builtin_amdgcn_mfma_f32_16x16x32_bf16(a1, b1, acc, 0, 0, 0);
    acc = __builtin_amdgcn_mfma_f32_16x16x32_bf16(a2, b2, acc, 0, 0, 0);
    acc = __builtin_amdgcn_mfma_f32_16x16x32_bf16(a3, b3, acc, 0, 0, 0);
#pragma unroll
    for (int r = 0; r < 4; ++r) {
      int row = nb + mt * 16 + quad * 4 + r;
      if (row < N) {
        float o = acc[r] + bv;
        C[(size_t)row * P + cb + col] = o;
        if (Cb) Cb[(size_t)row * 128 + cb + col] = f2bf(o);
      }
    }
  }
}

// ---- CSR build (by col) ----------------------------------------------------
__global__ void __launch_bounds__(256) k_hist(const int* __restrict__ eidx,
                                              int* __restrict__ cnt, int E) {
  int e = blockIdx.x * 256 + threadIdx.x;
  if (e < E) atomicAdd(&cnt[eidx[E + e]], 1);
}

__global__ void __launch_bounds__(256) k_scan(const int* __restrict__ cnt,
    int* __restrict__ ptr, int* __restrict__ cursor, int N) {
  __shared__ int sums[256];
  int t = threadIdx.x;
  int chunk = (N + 255) / 256;
  int lo = t * chunk;
  int hi = lo + chunk;
  if (hi > N) hi = N;
  if (lo > N) lo = N;
  int s = 0;
  for (int i = lo; i < hi; ++i) s += cnt[i];
  sums[t] = s;
  __syncthreads();
  for (int d = 1; d < 256; d <<= 1) {
    int v = (t >= d) ? sums[t - d] : 0;
    __syncthreads();
    sums[t] += v;
    __syncthreads();
  }
  int run = (t == 0) ? 0 : sums[t - 1];
  for (int i = lo; i < hi; ++i) {
    ptr[i] = run;
    cursor[i] = run;
    run += cnt[i];
  }
  if (t == 255) ptr[N] = run;
}

__global__ void __launch_bounds__(256) k_fill(const int* __restrict__ eidx,
    int* __restrict__ cursor, int* __restrict__ adjrow, int* __restrict__ perm,
    int E) {
  int e = blockIdx.x * 256 + threadIdx.x;
  if (e >= E) return;
  int r = eidx[e], c = eidx[E + e];
  int pos = atomicAdd(&cursor[c], 1);
  adjrow[pos] = r;
  perm[e] = pos;
}

// ---- exact expm of antisym 4x4 via so(4) = su(2) + su(2) -------------------
__device__ __forceinline__ void so4_expm(const float* __restrict__ m,
                                         float* __restrict__ F) {
  float v1 = m[1] - m[4], v2 = m[2] - m[8], v3 = m[3] - m[12];
  float w1 = m[11] - m[14], w2 = m[13] - m[7], w3 = m[6] - m[9];
  float p1 = 0.5f * (v1 + w1), p2 = 0.5f * (v2 + w2), p3 = 0.5f * (v3 + w3);
  float q1 = 0.5f * (v1 - w1), q2 = 0.5f * (v2 - w2), q3 = 0.5f * (v3 - w3);
  float tp2 = p1 * p1 + p2 * p2 + p3 * p3;
  float tq2 = q1 * q1 + q2 * q2 + q3 * q3;
  float tp = sqrtf(tp2), tq = sqrtf(tq2);
  float cp = __cosf(tp);
  float sp = (tp > 1e-6f) ? (__sinf(tp) / tp) : (1.f - tp2 * (1.f / 6.f));
  float cq = __cosf(tq);
  float sq = (tq > 1e-6f) ? (__sinf(tq) / tq) : (1.f - tq2 * (1.f / 6.f));
  float a1 = sp * p1, a2 = sp * p2, a3 = sp * p3;
  float b1 = sq * q1, b2 = sq * q2, b3 = sq * q3;
  float Rp[16] = {cp,  a1,  a2,  a3,  -a1, cp,  a3,  -a2,
                  -a2, -a3, cp,  a1,  -a3, a2,  -a1, cp};
  float Rq[16] = {cq,  b1,  b2,  b3,  -b1, cq,  -b3, b2,
                  -b2, b3,  cq,  -b1, -b3, -b2, b1,  cq};
#pragma unroll
  for (int a = 0; a < 4; ++a)
#pragma unroll
    for (int b = 0; b < 4; ++b) {
      float s = 0.f;
#pragma unroll
      for (int c = 0; c < 4; ++c) s = fmaf(Rp[a * 4 + c], Rq[c * 4 + b], s);
      F[a * 4 + b] = s;
    }
}

// 128 edges / 128-thread block, 2 straight-line K-chunks of 32 feats.
__global__ void __launch_bounds__(128) k_maps_expm(const float* __restrict__ pq,
    const float* __restrict__ w2, const float* __restrict__ b1,
    const float* __restrict__ b2, const int* __restrict__ eidx,
    const int* __restrict__ perm, float* __restrict__ MM, int E) {
  __shared__ float Hst[32 * 132];  // [feat_local][edge], stride 132
  int t = threadIdx.x;
  int w = t >> 6, lane = t & 63;
  int e0 = blockIdx.x * 128;
  int esub = lane >> 2, c4 = lane & 3;
  int rows[4], cols[4];
#pragma unroll
  for (int i = 0; i < 4; ++i) {
    int e = e0 + w * 64 + i * 16 + esub;
    int es = (e < E) ? e : (E - 1);
    rows[i] = eidx[es];
    cols[i] = eidx[E + es];
  }
  float acc[32];
#pragma unroll
  for (int o = 0; o < 32; ++o) acc[o] = b2[o];  // uniform -> s_load

  // ---- chunk 0: features 0..31 ----
#pragma unroll
  for (int i = 0; i < 4; ++i) {
    int eloc = w * 64 + i * 16 + esub;
#pragma unroll
    for (int j = 0; j < 2; ++j) {
      int fl = j * 16 + c4 * 4;
      float4 pv = *(const float4*)(pq + (size_t)rows[i] * 128 + fl);
      float4 qv = *(const float4*)(pq + (size_t)cols[i] * 128 + 64 + fl);
      float4 bv = *(const float4*)(b1 + fl);
      Hst[(fl + 0) * 132 + eloc] = fmaxf(pv.x + qv.x + bv.x, 0.f);
      Hst[(fl + 1) * 132 + eloc] = fmaxf(pv.y + qv.y + bv.y, 0.f);
      Hst[(fl + 2) * 132 + eloc] = fmaxf(pv.z + qv.z + bv.z, 0.f);
      Hst[(fl + 3) * 132 + eloc] = fmaxf(pv.w + qv.w + bv.w, 0.f);
    }
  }
  __syncthreads();
  for (int m = 0; m < 32; ++m) {
    float hm = Hst[m * 132 + t];  // stride-1 across lanes
#pragma unroll
    for (int o = 0; o < 32; ++o)
      acc[o] = fmaf(hm, w2[m * 32 + o], acc[o]);  // s_load
  }
  __syncthreads();

  // ---- chunk 1: features 32..63 ----
#pragma unroll
  for (int i = 0; i < 4; ++i) {
    int eloc = w * 64 + i * 16 + esub;
#pragma unroll
    for (int j = 0; j < 2; ++j) {
      int fl = j * 16 + c4 * 4;
      int f = 32 + fl;
      float4 pv = *(const float4*)(pq + (size_t)rows[i] * 128 + f);
      float4 qv = *(const float4*)(pq + (size_t)cols[i] * 128 + 64 + f);
      float4 bv = *(const float4*)(b1 + f);
      Hst[(fl + 0) * 132 + eloc] = fmaxf(pv.x + qv.x + bv.x, 0.f);
      Hst[(fl + 1) * 132 + eloc] = fmaxf(pv.y + qv.y + bv.y, 0.f);
      Hst[(fl + 2) * 132 + eloc] = fmaxf(pv.z + qv.z + bv.z, 0.f);
      Hst[(fl + 3) * 132 + eloc] = fmaxf(pv.w + qv.w + bv.w, 0.f);
    }
  }
  __syncthreads();
  for (int m = 0; m < 32; ++m) {
    float hm = Hst[m * 132 + t];
#pragma unroll
    for (int o = 0; o < 32; ++o)
      acc[o] = fmaf(hm, w2[(32 + m) * 32 + o], acc[o]);  // s_load
  }

  int e = e0 + t;
  if (e >= E) return;
  float Fu[16], Fv[16];
  so4_expm(acc, Fu);
  so4_expm(acc + 16, Fv);
  float out[32];
#pragma unroll
  for (int a = 0; a < 4; ++a)
#pragma unroll
    for (int b = 0; b < 4; ++b) {
      float s1 = 0.f, s2 = 0.f;
#pragma unroll
      for (int c = 0; c < 4; ++c) {
        s1 = fmaf(Fu[c * 4 + a], Fu[c * 4 + b], s1);  // (Fu^T Fu)[a,b]
        s2 = fmaf(Fu[c * 4 + a], Fv[c * 4 + b], s2);  // (Fu^T Fv)[a,b]
      }
      out[a * 4 + b] = s1;
      out[16 + a * 4 + b] = s2;
    }
  float* mp = MM + (size_t)perm[e] * 32;
#pragma unroll
  for (int i = 0; i < 8; ++i) {
    float4 v = make_float4(out[i * 4], out[i * 4 + 1], out[i * 4 + 2],
                           out[i * 4 + 3]);
    *(float4*)(mp + i * 4) = v;
  }
}

// One wave per node: walk CSR segment (unroll-2), fused elu epilogue.
// Writes fp32 xout AND bf16 xoutb (next layer's MFMA A-operand).
__global__ void __launch_bounds__(256) k_agg(const float* __restrict__ x,
    const float* __restrict__ MM, const int* __restrict__ ptr,
    const int* __restrict__ adjrow, const float* __restrict__ epsp,
    float* __restrict__ xout, u16* __restrict__ xoutb, int N) {
  int wv = threadIdx.x >> 6, lane = threadIdx.x & 63;
  int v = blockIdx.x * 4 + wv;
  if (v >= N) return;
  int p0 = ptr[v], p1 = ptr[v + 1];
  int a = lane & 3, kb = lane & ~3;
  const float* xv = x + (size_t)v * 128;
  float4 xi1 = *(const float4*)(xv + kb);
  float4 xi2 = *(const float4*)(xv + 64 + kb);
  float hv1 = xv[lane], hv2 = xv[64 + lane];
  float acc1 = 0.f, acc2 = 0.f;
  int j = p0;
  for (; j + 1 < p1; j += 2) {
    int r0 = adjrow[j], r1 = adjrow[j + 1];
    const float* mpa = MM + (size_t)j * 32;
    const float* mpb = MM + (size_t)(j + 1) * 32;
    float4 am1 = *(const float4*)(mpa + a * 4);
    float4 am2 = *(const float4*)(mpa + 16 + a * 4);
    float4 bm1 = *(const float4*)(mpb + a * 4);
    float4 bm2 = *(const float4*)(mpb + 16 + a * 4);
    const float* xa = x + (size_t)r0 * 128;
    const float* xb = x + (size_t)r1 * 128;
    float4 xa1 = *(const float4*)(xa + kb);
    float4 xa2 = *(const float4*)(xa + 64 + kb);
    float4 xb1 = *(const float4*)(xb + kb);
    float4 xb2 = *(const float4*)(xb + 64 + kb);
    acc1 += am1.x * xi1.x + am1.y * xi1.y + am1.z * xi1.z + am1.w * xi1.w -
            (am2.x * xa1.x + am2.y * xa1.y + am2.z * xa1.z + am2.w * xa1.w);
    acc2 += am1.x * xi2.x + am1.y * xi2.y + am1.z * xi2.z + am1.w * xi2.w -
            (am2.x * xa2.x + am2.y * xa2.y + am2.z * xa2.z + am2.w * xa2.w);
    acc1 += bm1.x * xi1.x + bm1.y * xi1.y + bm1.z * xi1.z + bm1.w * xi1.w -
            (bm2.x * xb1.x + bm2.y * xb1.y + bm2.z * xb1.z + bm2.w * xb1.w);
    acc2 += bm1.x * xi2.x + bm1.y * xi2.y + bm1.z * xi2.z + bm1.w * xi2.w -
            (bm2.x * xb2.x + bm2.y * xb2.y + bm2.z * xb2.z + bm2.w * xb2.w);
  }
  if (j < p1) {
    int r0 = adjrow[j];
    const float* mpa = MM + (size_t)j * 32;
    float4 am1 = *(const float4*)(mpa + a * 4);
    float4 am2 = *(const float4*)(mpa + 16 + a * 4);
    const float* xa = x + (size_t)r0 * 128;
    float4 xa1 = *(const float4*)(xa + kb);
    float4 xa2 = *(const float4*)(xa + 64 + kb);
    acc1 += am1.x * xi1.x + am1.y * xi1.y + am1.z * xi1.z + am1.w * xi1.w -
            (am2.x * xa1.x + am2.y * xa1.y + am2.z * xa1.z + am2.w * xa1.w);
    acc2 += am1.x * xi2.x + am1.y * xi2.y + am1.z * xi2.z + am1.w * xi2.w -
            (am2.x * xa2.x + am2.y * xa2.y + am2.z * xa2.z + am2.w * xa2.w);
  }
  float eps = *epsp;
  float r1 = hv1 - eps * acc1;
  float r2 = hv2 - eps * acc2;
  r1 = (r1 > 0.f) ? r1 : expm1f(r1);
  r2 = (r2 > 0.f) ? r2 : expm1f(r2);
  xout[(size_t)v * 128 + lane] = r1;
  xout[(size_t)v * 128 + 64 + lane] = r2;
  xoutb[(size_t)v * 128 + lane] = f2bf(r1);
  xoutb[(size_t)v * 128 + 64 + lane] = f2bf(r2);
}

extern "C" void kernel_launch(void* const* d_in, const int* in_sizes, int n_in,
                              void* d_out, int out_size, void* d_ws,
                              size_t ws_size, hipStream_t stream) {
  const float* x = (const float*)d_in[0];
  const int* eidx = (const int*)d_in[1];
  const float* lin_in_w = (const float*)d_in[2];
  const float* lin_in_b = (const float*)d_in[3];
  const float* c0w1 = (const float*)d_in[4];
  const float* c0b1 = (const float*)d_in[5];
  const float* c0w2 = (const float*)d_in[6];
  const float* c0b2 = (const float*)d_in[7];
  const float* c0eps = (const float*)d_in[8];
  const float* c1w1 = (const float*)d_in[9];
  const float* c1b1 = (const float*)d_in[10];
  const float* c1w2 = (const float*)d_in[11];
  const float* c1b2 = (const float*)d_in[12];
  const float* c1eps = (const float*)d_in[13];
  const float* lout_w = (const float*)d_in[14];
  const float* lout_b = (const float*)d_in[15];
  float* out = (float*)d_out;

  int N = in_sizes[0] / 128;
  int E = in_sizes[1] / 2;
  int Npad = N + 64;

  char* ws = (char*)d_ws;
  size_t szH = (size_t)N * 128 * 4;
  size_t szHb = (size_t)Npad * 128 * 2;
  size_t szM = (size_t)E * 32 * 4;
  float* H = (float*)ws;
  float* H2 = (float*)(ws + szH);
  float* PQ = (float*)(ws + 2 * szH);
  float* MAPS = (float*)(ws + 3 * szH);
  u16* Xb = (u16*)(ws + 3 * szH + szM);
  u16* Hb = (u16*)(ws + 3 * szH + szM + szHb);
  u16* H2b = (u16*)(ws + 3 * szH + szM + 2 * szHb);
  u16* WTin = (u16*)(ws + 3 * szH + szM + 3 * szHb);
  u16* WT1a = WTin + 16384;
  u16* WT1b = WT1a + 16384;
  u16* WTout = WT1b + 16384;
  char* ip = (char*)(WTout + 8192);
  int* cnt = (int*)ip;                                   // N
  int* ptr = (int*)(ip + 4 * (size_t)(N + 64));          // N+1
  int* cursor = (int*)(ip + 8 * (size_t)(N + 64));       // N
  int* adjrow = (int*)(ip + 12 * (size_t)(N + 64));      // E
  int* perm = (int*)(ip + 12 * (size_t)(N + 64) + 4 * (size_t)E);  // E

  dim3 blk(256);
  int gN = (N + 63) / 64;
  int gE = (E + 255) / 256;

  // packs: x -> bf16, weights -> W^T bf16
  k_cvt_x<<<(N * 32 + 255) / 256, blk, 0, stream>>>(x, Xb, N * 32);
  k_pack_w<<<224, blk, 0, stream>>>(lin_in_w, c0w1, c1w1, lout_w, WTin, WT1a,
                                    WT1b, WTout);

  // CSR build
  hipMemsetAsync(cnt, 0, (size_t)N * 4, stream);
  k_hist<<<gE, blk, 0, stream>>>(eidx, cnt, E);
  k_scan<<<1, blk, 0, stream>>>(cnt, ptr, cursor, N);
  k_fill<<<gE, blk, 0, stream>>>(eidx, cursor, adjrow, perm, E);

  // h0 = x @ lin_in_w + b   (fp32 H + bf16 Hb)
  k_gemm_mfma<<<dim3(gN, 2), blk, 0, stream>>>(Xb, WTin, lin_in_b, H, Hb, N,
                                               128);

  float* cur = H;
  float* nxt = H2;
  u16* curb = Hb;
  u16* nxtb = H2b;
  for (int layer = 0; layer < 2; ++layer) {
    const u16* wt1 = layer ? WT1b : WT1a;
    const float* b1 = layer ? c1b1 : c0b1;
    const float* w2 = layer ? c1w2 : c0w2;
    const float* b2 = layer ? c1b2 : c0b2;
    const float* ep = layer ? c1eps : c0eps;
    k_gemm_mfma<<<dim3(gN, 2), blk, 0, stream>>>(curb, wt1, nullptr, PQ,
                                                 nullptr, N, 128);
    k_maps_expm<<<(E + 127) / 128, dim3(128), 0, stream>>>(PQ, w2, b1, b2,
                                                           eidx, perm, MAPS, E);
    k_agg<<<(N + 3) / 4, blk, 0, stream>>>(cur, MAPS, ptr, adjrow, ep, nxt,
                                           nxtb, N);
    float* tf = cur; cur = nxt; nxt = tf;
    u16* tb = curb; curb = nxtb; nxtb = tb;
  }

  // out = h @ lin_out_w + b
  k_gemm_mfma<<<dim3(gN, 1), blk, 0, stream>>>(curb, WTout, lout_b, out,
                                               nullptr, N, 64);
}

// Round 10
// 372.012 us; speedup vs baseline: 1.4757x; 1.0760x over previous
//
#include <hip/hip_runtime.h>
#include <math.h>

// ---------------------------------------------------------------------------
// SheafGNN forward. R10:
//  - MFMA GEMM re-grid: wave = 16x16 tile (K=128, 4 chained MFMAs), block =
//    4 waves, grid (N/64, P/16) -> ~10k waves (9.8/SIMD) vs 2.4 before.
//  - 3-phase parallel CSR scan (single-block scan was ~20-40us on one CU).
//  - k_maps_expm gathers PQ in bf16 (half the loads), LDS stride 133
//    (staged writes 2-way = free).
//  - k_agg unchanged (fp32 x for the self-term; emits bf16 copy for next
//    layer's MFMA A operand).
// ---------------------------------------------------------------------------

using short8 = __attribute__((ext_vector_type(8))) short;
using f32x4 = __attribute__((ext_vector_type(4))) float;
typedef unsigned short u16;

__device__ __forceinline__ u16 f2bf(float f) {  // RNE fp32->bf16
  unsigned u = __float_as_uint(f);
  unsigned r = (u + 0x7FFFu + ((u >> 16) & 1u)) >> 16;
  return (u16)r;
}
__device__ __forceinline__ float bf2f(u16 v) {
  return __uint_as_float(((unsigned)v) << 16);
}

// ---- one-time packs (also zeroes cnt for the CSR histogram) ----------------
__global__ void __launch_bounds__(256) k_cvt_x(const float* __restrict__ x,
                                               u16* __restrict__ Xb,
                                               int* __restrict__ cnt, int n4,
                                               int N) {
  int i = blockIdx.x * 256 + threadIdx.x;
  if (i < N) cnt[i] = 0;
  if (i >= n4) return;
  float4 v = ((const float4*)x)[i];
  ushort4 o;
  o.x = f2bf(v.x);
  o.y = f2bf(v.y);
  o.z = f2bf(v.z);
  o.w = f2bf(v.w);
  ((ushort4*)Xb)[i] = o;
}

__global__ void __launch_bounds__(256) k_pack_w(const float* __restrict__ win,
    const float* __restrict__ w1a, const float* __restrict__ w1b,
    const float* __restrict__ wout, u16* __restrict__ WTin,
    u16* __restrict__ WT1a, u16* __restrict__ WT1b, u16* __restrict__ WTout) {
  int idx = blockIdx.x * 256 + threadIdx.x;
  if (idx < 16384) {
    int o = idx >> 7, i = idx & 127;
    WTin[idx] = f2bf(win[i * 128 + o]);
  } else if (idx < 32768) {
    int j = idx - 16384;
    int o = j >> 7, i = j & 127;
    WT1a[j] = f2bf(o < 64 ? w1a[i * 64 + o] : w1a[(128 + i) * 64 + (o - 64)]);
  } else if (idx < 49152) {
    int j = idx - 32768;
    int o = j >> 7, i = j & 127;
    WT1b[j] = f2bf(o < 64 ? w1b[i * 64 + o] : w1b[(128 + i) * 64 + (o - 64)]);
  } else if (idx < 57344) {
    int j = idx - 49152;
    int o = j >> 7, i = j & 127;  // o < 64
    WTout[j] = f2bf(wout[i * 64 + o]);
  }
}

// ---- bf16 MFMA GEMM: wave = one 16x16 tile, K=128 --------------------------
// A[m=lane&15][k=quad*8+j] frags; B[n=lane&15][k=quad*8+j]; C/D col=lane&15,
// row=quad*4+reg (verified m89 mapping).
__global__ void __launch_bounds__(256) k_gemm_mfma(const u16* __restrict__ Ab,
    const u16* __restrict__ WT, const float* __restrict__ bias,
    float* __restrict__ C, u16* __restrict__ Cb, int N, int P) {
  int t = threadIdx.x;
  int wv = t >> 6, lane = t & 63;
  int row0 = (blockIdx.x << 6) + (wv << 4);
  int cb = blockIdx.y << 4;
  int col = lane & 15, quad = lane >> 4;
  const u16* wrow = WT + (size_t)(cb + col) * 128 + quad * 8;
  short8 b0 = *(const short8*)(wrow);
  short8 b1 = *(const short8*)(wrow + 32);
  short8 b2 = *(const short8*)(wrow + 64);
  short8 b3 = *(const short8*)(wrow + 96);
  float bv = bias ? bias[cb + col] : 0.f;
  const u16* ar = Ab + (size_t)(row0 + col) * 128 + quad * 8;
  short8 a0 = *(const short8*)(ar);
  short8 a1 = *(const short8*)(ar + 32);
  short8 a2 = *(const short8*)(ar + 64);
  short8 a3 = *(const short8*)(ar + 96);
  f32x4 acc = {0.f, 0.f, 0.f, 0.f};
  acc = __builtin_amdgcn_mfma_f32_16x16x32_bf16(a0, b0, acc, 0, 0, 0);
  acc = __builtin_amdgcn_mfma_f32_16x16x32_bf16(a1, b1, acc, 0, 0, 0);
  acc = __builtin_amdgcn_mfma_f32_16x16x32_bf16(a2, b2, acc, 0, 0, 0);
  acc = __builtin_amdgcn_mfma_f32_16x16x32_bf16(a3, b3, acc, 0, 0, 0);
#pragma unroll
  for (int r = 0; r < 4; ++r) {
    int row = row0 + quad * 4 + r;
    if (row < N) {
      float o = acc[r] + bv;
      if (C) C[(size_t)row * P + cb + col] = o;
      if (Cb) Cb[(size_t)row * 128 + cb + col] = f2bf(o);
    }
  }
}

// ---- CSR build (by col): hist -> 3-phase scan -> fill ----------------------
__global__ void __launch_bounds__(256) k_hist(const int* __restrict__ eidx,
                                              int* __restrict__ cnt, int E) {
  int e = blockIdx.x * 256 + threadIdx.x;
  if (e < E) atomicAdd(&cnt[eidx[E + e]], 1);
}

__global__ void __launch_bounds__(256) k_scanA(const int* __restrict__ cnt,
                                               int* __restrict__ bsum, int N) {
  __shared__ int sums[256];
  int b = blockIdx.x, t = threadIdx.x;
  int base = b * 2048 + t * 8;
  int s = 0;
#pragma unroll
  for (int k = 0; k < 8; ++k) {
    int i = base + k;
    if (i < N) s += cnt[i];
  }
  sums[t] = s;
  __syncthreads();
  for (int d = 128; d > 0; d >>= 1) {
    if (t < d) sums[t] += sums[t + d];
    __syncthreads();
  }
  if (t == 0) bsum[b] = sums[0];
}

__global__ void k_scanB(const int* __restrict__ bsum, int* __restrict__ boff,
                        int nb) {
  if (threadIdx.x == 0) {
    int run = 0;
    for (int b = 0; b < nb; ++b) {
      boff[b] = run;
      run += bsum[b];
    }
  }
}

__global__ void __launch_bounds__(256) k_scanC(const int* __restrict__ cnt,
    const int* __restrict__ boff, int* __restrict__ ptr,
    int* __restrict__ cursor, int N, int nblocks) {
  __shared__ int sums[256];
  int b = blockIdx.x, t = threadIdx.x;
  int base = b * 2048 + t * 8;
  int vals[8];
  int s = 0;
#pragma unroll
  for (int k = 0; k < 8; ++k) {
    int i = base + k;
    int c = (i < N) ? cnt[i] : 0;
    vals[k] = s;
    s += c;
  }
  sums[t] = s;
  __syncthreads();
  for (int d = 1; d < 256; d <<= 1) {
    int v = (t >= d) ? sums[t - d] : 0;
    __syncthreads();
    sums[t] += v;
    __syncthreads();
  }
  int toff = (t == 0) ? 0 : sums[t - 1];
  int bo = boff[b];
#pragma unroll
  for (int k = 0; k < 8; ++k) {
    int i = base + k;
    if (i < N) {
      int p = bo + toff + vals[k];
      ptr[i] = p;
      cursor[i] = p;
    }
  }
  if (b == nblocks - 1 && t == 255) ptr[N] = bo + sums[255];
}

__global__ void __launch_bounds__(256) k_fill(const int* __restrict__ eidx,
    int* __restrict__ cursor, int* __restrict__ adjrow, int* __restrict__ perm,
    int E) {
  int e = blockIdx.x * 256 + threadIdx.x;
  if (e >= E) return;
  int r = eidx[e], c = eidx[E + e];
  int pos = atomicAdd(&cursor[c], 1);
  adjrow[pos] = r;
  perm[e] = pos;
}

// ---- exact expm of antisym 4x4 via so(4) = su(2) + su(2) -------------------
__device__ __forceinline__ void so4_expm(const float* __restrict__ m,
                                         float* __restrict__ F) {
  float v1 = m[1] - m[4], v2 = m[2] - m[8], v3 = m[3] - m[12];
  float w1 = m[11] - m[14], w2 = m[13] - m[7], w3 = m[6] - m[9];
  float p1 = 0.5f * (v1 + w1), p2 = 0.5f * (v2 + w2), p3 = 0.5f * (v3 + w3);
  float q1 = 0.5f * (v1 - w1), q2 = 0.5f * (v2 - w2), q3 = 0.5f * (v3 - w3);
  float tp2 = p1 * p1 + p2 * p2 + p3 * p3;
  float tq2 = q1 * q1 + q2 * q2 + q3 * q3;
  float tp = sqrtf(tp2), tq = sqrtf(tq2);
  float cp = __cosf(tp);
  float sp = (tp > 1e-6f) ? (__sinf(tp) / tp) : (1.f - tp2 * (1.f / 6.f));
  float cq = __cosf(tq);
  float sq = (tq > 1e-6f) ? (__sinf(tq) / tq) : (1.f - tq2 * (1.f / 6.f));
  float a1 = sp * p1, a2 = sp * p2, a3 = sp * p3;
  float b1 = sq * q1, b2 = sq * q2, b3 = sq * q3;
  float Rp[16] = {cp,  a1,  a2,  a3,  -a1, cp,  a3,  -a2,
                  -a2, -a3, cp,  a1,  -a3, a2,  -a1, cp};
  float Rq[16] = {cq,  b1,  b2,  b3,  -b1, cq,  -b3, b2,
                  -b2, b3,  cq,  -b1, -b3, -b2, b1,  cq};
#pragma unroll
  for (int a = 0; a < 4; ++a)
#pragma unroll
    for (int b = 0; b < 4; ++b) {
      float s = 0.f;
#pragma unroll
      for (int c = 0; c < 4; ++c) s = fmaf(Rp[a * 4 + c], Rq[c * 4 + b], s);
      F[a * 4 + b] = s;
    }
}

// 128 edges / 128-thread block, 2 straight-line K-chunks of 32 feats.
// PQ gathered in bf16 (short8 = 8 feats / load). LDS stride 133: staged
// writes are exactly 2-way bank-aliased (free), reads conflict-free.
__global__ void __launch_bounds__(128) k_maps_expm(const u16* __restrict__ pqb,
    const float* __restrict__ w2, const float* __restrict__ b1,
    const float* __restrict__ b2, const int* __restrict__ eidx,
    const int* __restrict__ perm, float* __restrict__ MM, int E) {
  __shared__ float Hst[32 * 133];  // [feat_local][edge]
  int t = threadIdx.x;
  int w = t >> 6, lane = t & 63;
  int e0 = blockIdx.x * 128;
  int esub = lane >> 2, c4 = lane & 3;
  int rows[4], cols[4];
#pragma unroll
  for (int i = 0; i < 4; ++i) {
    int e = e0 + w * 64 + i * 16 + esub;
    int es = (e < E) ? e : (E - 1);
    rows[i] = eidx[es];
    cols[i] = eidx[E + es];
  }
  float acc[32];
#pragma unroll
  for (int o = 0; o < 32; ++o) acc[o] = b2[o];  // uniform -> s_load

  // ---- chunk 0: features 0..31 ----
#pragma unroll
  for (int i = 0; i < 4; ++i) {
    int eloc = w * 64 + i * 16 + esub;
    short8 pv = *(const short8*)(pqb + (size_t)rows[i] * 128 + c4 * 8);
    short8 qv = *(const short8*)(pqb + (size_t)cols[i] * 128 + 64 + c4 * 8);
#pragma unroll
    for (int k = 0; k < 8; ++k) {
      int f = c4 * 8 + k;
      float vv = bf2f((u16)pv[k]) + bf2f((u16)qv[k]) + b1[f];
      Hst[f * 133 + eloc] = fmaxf(vv, 0.f);
    }
  }
  __syncthreads();
  for (int m = 0; m < 32; ++m) {
    float hm = Hst[m * 133 + t];  // stride-1 across lanes
#pragma unroll
    for (int o = 0; o < 32; ++o)
      acc[o] = fmaf(hm, w2[m * 32 + o], acc[o]);  // s_load
  }
  __syncthreads();

  // ---- chunk 1: features 32..63 ----
#pragma unroll
  for (int i = 0; i < 4; ++i) {
    int eloc = w * 64 + i * 16 + esub;
    short8 pv = *(const short8*)(pqb + (size_t)rows[i] * 128 + 32 + c4 * 8);
    short8 qv =
        *(const short8*)(pqb + (size_t)cols[i] * 128 + 96 + c4 * 8);
#pragma unroll
    for (int k = 0; k < 8; ++k) {
      int f = c4 * 8 + k;
      float vv = bf2f((u16)pv[k]) + bf2f((u16)qv[k]) + b1[32 + f];
      Hst[f * 133 + eloc] = fmaxf(vv, 0.f);
    }
  }
  __syncthreads();
  for (int m = 0; m < 32; ++m) {
    float hm = Hst[m * 133 + t];
#pragma unroll
    for (int o = 0; o < 32; ++o)
      acc[o] = fmaf(hm, w2[(32 + m) * 32 + o], acc[o]);  // s_load
  }

  int e = e0 + t;
  if (e >= E) return;
  float Fu[16], Fv[16];
  so4_expm(acc, Fu);
  so4_expm(acc + 16, Fv);
  float out[32];
#pragma unroll
  for (int a = 0; a < 4; ++a)
#pragma unroll
    for (int b = 0; b < 4; ++b) {
      float s1 = 0.f, s2 = 0.f;
#pragma unroll
      for (int c = 0; c < 4; ++c) {
        s1 = fmaf(Fu[c * 4 + a], Fu[c * 4 + b], s1);  // (Fu^T Fu)[a,b]
        s2 = fmaf(Fu[c * 4 + a], Fv[c * 4 + b], s2);  // (Fu^T Fv)[a,b]
      }
      out[a * 4 + b] = s1;
      out[16 + a * 4 + b] = s2;
    }
  float* mp = MM + (size_t)perm[e] * 32;
#pragma unroll
  for (int i = 0; i < 8; ++i) {
    float4 v = make_float4(out[i * 4], out[i * 4 + 1], out[i * 4 + 2],
                           out[i * 4 + 3]);
    *(float4*)(mp + i * 4) = v;
  }
}

// One wave per node: walk CSR segment (unroll-2), fused elu epilogue.
// Writes fp32 xout AND bf16 xoutb (next layer's MFMA A-operand).
__global__ void __launch_bounds__(256) k_agg(const float* __restrict__ x,
    const float* __restrict__ MM, const int* __restrict__ ptr,
    const int* __restrict__ adjrow, const float* __restrict__ epsp,
    float* __restrict__ xout, u16* __restrict__ xoutb, int N) {
  int wv = threadIdx.x >> 6, lane = threadIdx.x & 63;
  int v = blockIdx.x * 4 + wv;
  if (v >= N) return;
  int p0 = ptr[v], p1 = ptr[v + 1];
  int a = lane & 3, kb = lane & ~3;
  const float* xv = x + (size_t)v * 128;
  float4 xi1 = *(const float4*)(xv + kb);
  float4 xi2 = *(const float4*)(xv + 64 + kb);
  float hv1 = xv[lane], hv2 = xv[64 + lane];
  float acc1 = 0.f, acc2 = 0.f;
  int j = p0;
  for (; j + 1 < p1; j += 2) {
    int r0 = adjrow[j], r1 = adjrow[j + 1];
    const float* mpa = MM + (size_t)j * 32;
    const float* mpb = MM + (size_t)(j + 1) * 32;
    float4 am1 = *(const float4*)(mpa + a * 4);
    float4 am2 = *(const float4*)(mpa + 16 + a * 4);
    float4 bm1 = *(const float4*)(mpb + a * 4);
    float4 bm2 = *(const float4*)(mpb + 16 + a * 4);
    const float* xa = x + (size_t)r0 * 128;
    const float* xb = x + (size_t)r1 * 128;
    float4 xa1 = *(const float4*)(xa + kb);
    float4 xa2 = *(const float4*)(xa + 64 + kb);
    float4 xb1 = *(const float4*)(xb + kb);
    float4 xb2 = *(const float4*)(xb + 64 + kb);
    acc1 += am1.x * xi1.x + am1.y * xi1.y + am1.z * xi1.z + am1.w * xi1.w -
            (am2.x * xa1.x + am2.y * xa1.y + am2.z * xa1.z + am2.w * xa1.w);
    acc2 += am1.x * xi2.x + am1.y * xi2.y + am1.z * xi2.z + am1.w * xi2.w -
            (am2.x * xa2.x + am2.y * xa2.y + am2.z * xa2.z + am2.w * xa2.w);
    acc1 += bm1.x * xi1.x + bm1.y * xi1.y + bm1.z * xi1.z + bm1.w * xi1.w -
            (bm2.x * xb1.x + bm2.y * xb1.y + bm2.z * xb1.z + bm2.w * xb1.w);
    acc2 += bm1.x * xi2.x + bm1.y * xi2.y + bm1.z * xi2.z + bm1.w * xi2.w -
            (bm2.x * xb2.x + bm2.y * xb2.y + bm2.z * xb2.z + bm2.w * xb2.w);
  }
  if (j < p1) {
    int r0 = adjrow[j];
    const float* mpa = MM + (size_t)j * 32;
    float4 am1 = *(const float4*)(mpa + a * 4);
    float4 am2 = *(const float4*)(mpa + 16 + a * 4);
    const float* xa = x + (size_t)r0 * 128;
    float4 xa1 = *(const float4*)(xa + kb);
    float4 xa2 = *(const float4*)(xa + 64 + kb);
    acc1 += am1.x * xi1.x + am1.y * xi1.y + am1.z * xi1.z + am1.w * xi1.w -
            (am2.x * xa1.x + am2.y * xa1.y + am2.z * xa1.z + am2.w * xa1.w);
    acc2 += am1.x * xi2.x + am1.y * xi2.y + am1.z * xi2.z + am1.w * xi2.w -
            (am2.x * xa2.x + am2.y * xa2.y + am2.z * xa2.z + am2.w * xa2.w);
  }
  float eps = *epsp;
  float r1 = hv1 - eps * acc1;
  float r2 = hv2 - eps * acc2;
  r1 = (r1 > 0.f) ? r1 : expm1f(r1);
  r2 = (r2 > 0.f) ? r2 : expm1f(r2);
  xout[(size_t)v * 128 + lane] = r1;
  xout[(size_t)v * 128 + 64 + lane] = r2;
  xoutb[(size_t)v * 128 + lane] = f2bf(r1);
  xoutb[(size_t)v * 128 + 64 + lane] = f2bf(r2);
}

extern "C" void kernel_launch(void* const* d_in, const int* in_sizes, int n_in,
                              void* d_out, int out_size, void* d_ws,
                              size_t ws_size, hipStream_t stream) {
  const float* x = (const float*)d_in[0];
  const int* eidx = (const int*)d_in[1];
  const float* lin_in_w = (const float*)d_in[2];
  const float* lin_in_b = (const float*)d_in[3];
  const float* c0w1 = (const float*)d_in[4];
  const float* c0b1 = (const float*)d_in[5];
  const float* c0w2 = (const float*)d_in[6];
  const float* c0b2 = (const float*)d_in[7];
  const float* c0eps = (const float*)d_in[8];
  const float* c1w1 = (const float*)d_in[9];
  const float* c1b1 = (const float*)d_in[10];
  const float* c1w2 = (const float*)d_in[11];
  const float* c1b2 = (const float*)d_in[12];
  const float* c1eps = (const float*)d_in[13];
  const float* lout_w = (const float*)d_in[14];
  const float* lout_b = (const float*)d_in[15];
  float* out = (float*)d_out;

  int N = in_sizes[0] / 128;
  int E = in_sizes[1] / 2;
  int Npad = N + 64;

  char* ws = (char*)d_ws;
  size_t szH = (size_t)N * 128 * 4;
  size_t szHb = (size_t)Npad * 128 * 2;
  size_t szM = (size_t)E * 32 * 4;
  float* H = (float*)ws;
  float* H2 = (float*)(ws + szH);
  float* MAPS = (float*)(ws + 2 * szH);
  u16* Xb = (u16*)(ws + 2 * szH + szM);
  u16* Hb = (u16*)(ws + 2 * szH + szM + szHb);
  u16* H2b = (u16*)(ws + 2 * szH + szM + 2 * szHb);
  u16* PQb = (u16*)(ws + 2 * szH + szM + 3 * szHb);
  u16* WTin = (u16*)(ws + 2 * szH + szM + 4 * szHb);
  u16* WT1a = WTin + 16384;
  u16* WT1b = WT1a + 16384;
  u16* WTout = WT1b + 16384;
  char* ip = (char*)(WTout + 8192);
  int* cnt = (int*)ip;                                   // N
  int* ptr = (int*)(ip + 4 * (size_t)(N + 64));          // N+1
  int* cursor = (int*)(ip + 8 * (size_t)(N + 64));       // N
  int* adjrow = (int*)(ip + 12 * (size_t)(N + 64));      // E
  int* perm = (int*)(ip + 12 * (size_t)(N + 64) + 4 * (size_t)E);  // E
  int* bsum = perm + E;                                  // 64
  int* boff = bsum + 64;                                 // 64

  dim3 blk(256);
  int gN = (N + 63) / 64;
  int gE = (E + 255) / 256;
  int nsb = (N + 2047) / 2048;

  // packs (+cnt zero), CSR build
  k_cvt_x<<<(N * 32 + 255) / 256, blk, 0, stream>>>(x, Xb, cnt, N * 32, N);
  k_pack_w<<<224, blk, 0, stream>>>(lin_in_w, c0w1, c1w1, lout_w, WTin, WT1a,
                                    WT1b, WTout);
  k_hist<<<gE, blk, 0, stream>>>(eidx, cnt, E);
  k_scanA<<<nsb, blk, 0, stream>>>(cnt, bsum, N);
  k_scanB<<<1, dim3(64), 0, stream>>>(bsum, boff, nsb);
  k_scanC<<<nsb, blk, 0, stream>>>(cnt, boff, ptr, cursor, N, nsb);
  k_fill<<<gE, blk, 0, stream>>>(eidx, cursor, adjrow, perm, E);

  // h0 = x @ lin_in_w + b   (fp32 H + bf16 Hb)
  k_gemm_mfma<<<dim3(gN, 8), blk, 0, stream>>>(Xb, WTin, lin_in_b, H, Hb, N,
                                               128);

  float* cur = H;
  float* nxt = H2;
  u16* curb = Hb;
  u16* nxtb = H2b;
  for (int layer = 0; layer < 2; ++layer) {
    const u16* wt1 = layer ? WT1b : WT1a;
    const float* b1 = layer ? c1b1 : c0b1;
    const float* w2 = layer ? c1w2 : c0w2;
    const float* b2 = layer ? c1b2 : c0b2;
    const float* ep = layer ? c1eps : c0eps;
    k_gemm_mfma<<<dim3(gN, 8), blk, 0, stream>>>(curb, wt1, nullptr, nullptr,
                                                 PQb, N, 128);
    k_maps_expm<<<(E + 127) / 128, dim3(128), 0, stream>>>(PQb, w2, b1, b2,
                                                           eidx, perm, MAPS, E);
    k_agg<<<(N + 3) / 4, blk, 0, stream>>>(cur, MAPS, ptr, adjrow, ep, nxt,
                                           nxtb, N);
    float* tf = cur; cur = nxt; nxt = tf;
    u16* tb = curb; curb = nxtb; nxtb = tb;
  }

  // out = h @ lin_out_w + b
  k_gemm_mfma<<<dim3(gN, 4), blk, 0, stream>>>(curb, WTout, lout_b, out,
                                               nullptr, N, 64);
}